// Round 18
// baseline (161.448 us; speedup 1.0000x reference)
//
#include <hip/hip_runtime.h>
#include <hip/hip_bf16.h>
#include <cmath>

// Problem constants
#define BATCH   64
#define NPG     1024           // nodes per graph
#define NODES   65536          // BATCH*NPG
#define EDGES   524288
#define EPG     8192           // edges per graph (contiguous slice!)
#define FIN     14
#define NH      128
#define KP1     820
#define KP2     656
#define ASTR    15             // padded LDS stride for FIN tiles (2-way, free)
#define NG2BLK  16384          // gather2 blocks in merged dispatch

typedef __attribute__((ext_vector_type(8))) short bf16x8;
typedef __attribute__((ext_vector_type(4))) float f32x4;

static __device__ __forceinline__ unsigned short f2bf(float f) {
  __hip_bfloat16 h = __float2bfloat16(f);
  return *reinterpret_cast<unsigned short*>(&h);
}
static __device__ __forceinline__ float bf2f(unsigned int u16) {
  return __uint_as_float(u16 << 16);
}

// ---------------------------------------------------------------------------
// CSR build + Wfrag prep in ONE dispatch.
// Blocks 0..63: per-graph CSR; scan is wave-level (__shfl_up, 5 barriers
// instead of 22). Blocks 64..67: bf16 W2 fragment table.
// NOTE (r16 lesson): x stays f32 — bf16-izing conv1 inputs perturbs s1 and
// flips top-k boundary ranks (top-k is discontinuous in the score).
// ---------------------------------------------------------------------------
__global__ __launch_bounds__(1024) void k_csr(
    const int* __restrict__ src, const int* __restrict__ dst,
    int* __restrict__ rowptr, int* __restrict__ col,
    const float* __restrict__ W2rel, const float* __restrict__ W2rt,
    unsigned short* __restrict__ Wfrag) {
  int g = blockIdx.x, t = threadIdx.x;
  if (g >= BATCH) {                           // Wfrag builder blocks
    int id = (g - BATCH) * 1024 + t;          // 0..4095
    int lane = id & 63, sg = (id >> 6) & 7, c = id >> 9;
    const float* SW = (sg < 4) ? W2rel : W2rt;
    int o = c * 16 + (lane & 15);
    int k = (sg & 3) * 32 + (lane >> 4) * 8;
    float4 f0 = *(const float4*)(SW + (size_t)o * NH + k);
    float4 f1 = *(const float4*)(SW + (size_t)o * NH + k + 4);
    union { unsigned short us[8]; uint4 v; } p;
    p.us[0] = f2bf(f0.x); p.us[1] = f2bf(f0.y);
    p.us[2] = f2bf(f0.z); p.us[3] = f2bf(f0.w);
    p.us[4] = f2bf(f1.x); p.us[5] = f2bf(f1.y);
    p.us[6] = f2bf(f1.z); p.us[7] = f2bf(f1.w);
    *(uint4*)(Wfrag + (size_t)id * 8) = p.v;
    return;
  }
  __shared__ int cnt[NPG];
  __shared__ int wsum[16];
  int ebase = g * EPG;
  cnt[t] = 0;
  __syncthreads();
  int dl[8], sl[8];
#pragma unroll
  for (int i = 0; i < 8; ++i) {
    int e = ebase + t + i * 1024;
    dl[i] = dst[e] - g * NPG;
    sl[i] = src[e];
    atomicAdd(&cnt[dl[i]], 1);
  }
  __syncthreads();
  int v = cnt[t];
  int lane = t & 63, wid = t >> 6;
  int incl = v;                               // wave-level inclusive scan
#pragma unroll
  for (int d = 1; d < 64; d <<= 1) {
    int o = __shfl_up(incl, d);
    if (lane >= d) incl += o;
  }
  if (lane == 63) wsum[wid] = incl;
  __syncthreads();
  if (wid == 0) {
    int wv = (lane < 16) ? wsum[lane] : 0;
    int wi = wv;
#pragma unroll
    for (int d = 1; d < 16; d <<= 1) {
      int o = __shfl_up(wi, d);
      if (lane >= d) wi += o;
    }
    if (lane < 16) wsum[lane] = wi - wv;      // exclusive wave base
  }
  __syncthreads();
  int excl = incl - v + wsum[wid];
  rowptr[g * NPG + t] = ebase + excl;
  if (g == 0 && t == 0) rowptr[NODES] = EDGES;
  __syncthreads();
  cnt[t] = excl;                              // becomes local cursor
  __syncthreads();
#pragma unroll
  for (int i = 0; i < 8; ++i) {
    int pos = atomicAdd(&cnt[dl[i]], 1);
    col[ebase + pos] = sl[i];
  }
}

// ---------------------------------------------------------------------------
// conv1 aggregation via CSR gather over f32 x (score-path precision).
// Col indices preloaded per 16-lane group + shfl broadcast (no serial
// col[j] chain); 4 independent x-row loads in flight. XCD-swizzled.
// Lanes 14/15 clamp to feature 13 (same cacheline, no OOB, result unused).
// ---------------------------------------------------------------------------
__global__ __launch_bounds__(256) void k_gather1(
    const float* __restrict__ x, const int* __restrict__ rowptr,
    const int* __restrict__ col, float* __restrict__ agg1) {
  int bid = blockIdx.x;                       // 4096 blocks, 512 per XCD chunk
  int swz = (bid & 7) * 512 + (bid >> 3);
  int t = threadIdx.x;
  int gi = t >> 4;                            // node slot in block (0..15)
  int lane = t & 63;
  int sub = lane & 15;                        // position within 16-lane group
  int gb = lane & 48;                         // group base within wave
  int su = sub < FIN ? sub : FIN - 1;         // clamped feature index
  int n = swz * 16 + gi;
  int rs = rowptr[n], re = rowptr[n + 1];
  int deg = re - rs;
  int colv = (sub < deg) ? col[rs + sub] : 0;
  int m = deg < 16 ? deg : 16;
  float acc = 0.f;
  int nfull = m & ~3;
  int j = 0;
  for (; j < nfull; j += 4) {
    int v0 = __shfl(colv, gb + j);
    int v1 = __shfl(colv, gb + j + 1);
    int v2 = __shfl(colv, gb + j + 2);
    int v3 = __shfl(colv, gb + j + 3);
    float a0 = x[(size_t)v0 * FIN + su];
    float a1 = x[(size_t)v1 * FIN + su];
    float a2 = x[(size_t)v2 * FIN + su];
    float a3 = x[(size_t)v3 * FIN + su];
    acc += a0 + a1 + a2 + a3;
  }
  for (; j < m; ++j) {
    int v = __shfl(colv, gb + j);
    acc += x[(size_t)v * FIN + su];
  }
  for (int jj = rs + 16; jj < re; ++jj) {     // deg>16 fallback (~0.3%)
    int v = col[jj];
    acc += x[(size_t)v * FIN + su];
  }
  if (sub < FIN) agg1[(size_t)n * FIN + sub] = acc;
}

// ---------------------------------------------------------------------------
// conv1 GEMM + relu + fused pool1 score; OUTPUT IS BF16 (h only; s1 is f32
// from f32 inputs -> top-k decisions match reference). LDS stride ASTR=15.
// ---------------------------------------------------------------------------
__global__ __launch_bounds__(256) void k_gemm1(
    const float* __restrict__ x, const float* __restrict__ agg1,
    const float* __restrict__ Wrel, const float* __restrict__ brel,
    const float* __restrict__ Wroot, const float* __restrict__ p1w,
    unsigned short* __restrict__ hbf1, float* __restrict__ s1) {
  __shared__ float As[64 * ASTR];
  __shared__ float Xs[64 * ASTR];
  __shared__ float Wl[2 * FIN][NH];
  int t = threadIdx.x;
  int nb = blockIdx.x * 64;
  for (int i = t; i < 64 * FIN; i += 256) {
    int n = i / FIN, k = i - n * FIN;
    As[n * ASTR + k] = agg1[(size_t)nb * FIN + i];
    Xs[n * ASTR + k] = x[(size_t)nb * FIN + i];
  }
  for (int i = t; i < NH * FIN; i += 256) {
    int o = i / FIN, k = i - o * FIN;
    Wl[k][o]       = Wrel[i];
    Wl[k + FIN][o] = Wroot[i];
  }
  __syncthreads();
  int og = t & 15, ng = t >> 4, ra = ng * 4;
  float bb[8], pw[8];
#pragma unroll
  for (int j = 0; j < 4; ++j) {
    int c0 = og * 4 + j, c1 = 64 + og * 4 + j;
    bb[j] = brel[c0]; bb[j + 4] = brel[c1];
    pw[j] = p1w[c0];  pw[j + 4] = p1w[c1];
  }
  float q = 0.f;
#pragma unroll
  for (int j = 0; j < 8; ++j) q += pw[j] * pw[j];
  q += __shfl_xor(q, 1); q += __shfl_xor(q, 2);
  q += __shfl_xor(q, 4); q += __shfl_xor(q, 8);
  float rnorm = rsqrtf(q);

  float acc[4][8];
#pragma unroll
  for (int i = 0; i < 4; ++i)
#pragma unroll
    for (int j = 0; j < 8; ++j) acc[i][j] = bb[j];
#pragma unroll
  for (int k = 0; k < FIN; ++k) {
    float4 w0 = *(const float4*)&Wl[k][og * 4];
    float4 w1 = *(const float4*)&Wl[k][64 + og * 4];
#pragma unroll
    for (int i = 0; i < 4; ++i) {
      float a = As[(ra + i) * ASTR + k];
      acc[i][0] += a * w0.x; acc[i][1] += a * w0.y;
      acc[i][2] += a * w0.z; acc[i][3] += a * w0.w;
      acc[i][4] += a * w1.x; acc[i][5] += a * w1.y;
      acc[i][6] += a * w1.z; acc[i][7] += a * w1.w;
    }
  }
#pragma unroll
  for (int k = 0; k < FIN; ++k) {
    float4 w0 = *(const float4*)&Wl[FIN + k][og * 4];
    float4 w1 = *(const float4*)&Wl[FIN + k][64 + og * 4];
#pragma unroll
    for (int i = 0; i < 4; ++i) {
      float a = Xs[(ra + i) * ASTR + k];
      acc[i][0] += a * w0.x; acc[i][1] += a * w0.y;
      acc[i][2] += a * w0.z; acc[i][3] += a * w0.w;
      acc[i][4] += a * w1.x; acc[i][5] += a * w1.y;
      acc[i][6] += a * w1.z; acc[i][7] += a * w1.w;
    }
  }
#pragma unroll
  for (int i = 0; i < 4; ++i) {
    int n = nb + ra + i;
    float pv = 0.f;
    union { unsigned short us[4]; uint2 v; } o0, o1;
#pragma unroll
    for (int j = 0; j < 4; ++j) {
      float v0 = fmaxf(acc[i][j], 0.f);
      float v1 = fmaxf(acc[i][4 + j], 0.f);
      pv += v0 * pw[j] + v1 * pw[4 + j];
      o0.us[j] = f2bf(v0);
      o1.us[j] = f2bf(v1);
    }
    *(uint2*)(hbf1 + (size_t)n * NH + og * 4) = o0.v;
    *(uint2*)(hbf1 + (size_t)n * NH + 64 + og * 4) = o1.v;
    pv += __shfl_xor(pv, 1);
    pv += __shfl_xor(pv, 2);
    pv += __shfl_xor(pv, 4);
    pv += __shfl_xor(pv, 8);
    if (og == 0) s1[n] = tanhf(pv * rnorm);
  }
}

// ---------------------------------------------------------------------------
// exact per-graph top-K: 512 threads, bitonic over 1024 keys; j<=64 stages
// are wave-local. Writes sm_out[n] = kept ? score[n] : 0 (sole kept signal).
// ---------------------------------------------------------------------------
__global__ __launch_bounds__(512) void k_topk(
    const float* __restrict__ score, const float* __restrict__ mask_sm,
    float* __restrict__ sm_out, int K) {
  __shared__ unsigned long long keys[1024];
  int t = threadIdx.x, g = blockIdx.x;
  for (int i = t; i < 1024; i += 512) {
    int n = g * NPG + i;
    unsigned int inv;
    if (mask_sm && mask_sm[n] == 0.f) {
      inv = 0xFFFFFFFFu;
    } else {
      unsigned int u   = __float_as_uint(score[n]);
      unsigned int ord = (u & 0x80000000u) ? ~u : (u | 0x80000000u);
      inv = ~ord;
    }
    keys[i] = ((unsigned long long)inv << 32) | (unsigned int)i;
  }
  __syncthreads();
  for (int k = 2; k <= 1024; k <<= 1) {
    int j = k >> 1;
    for (; j >= 128; j >>= 1) {            // cross-wave stages
      int i = ((t & ~(j - 1)) << 1) | (t & (j - 1));
      int p = i | j;
      unsigned long long a = keys[i], b = keys[p];
      bool up = ((i & k) == 0);
      if ((a > b) == up) { keys[i] = b; keys[p] = a; }
      __syncthreads();
    }
    for (; j > 0; j >>= 1) {               // wave-local stages
      int i = ((t & ~(j - 1)) << 1) | (t & (j - 1));
      int p = i | j;
      unsigned long long a = keys[i], b = keys[p];
      bool up = ((i & k) == 0);
      if ((a > b) == up) { keys[i] = b; keys[p] = a; }
      asm volatile("" ::: "memory");
    }
    __syncthreads();
  }
  for (int i = t; i < 1024; i += 512) {
    int idx = (int)(keys[i] & 0xFFFFFFFFu);
    int n = g * NPG + idx;
    sm_out[n] = (i < K) ? score[n] : 0.f;
  }
}

// ---------------------------------------------------------------------------
// MERGED dispatch: gather2 (blocks 0..16383) + readout1 (blocks 16384..17407).
// All gating on s1m != 0 (kept nodes have s!=0 a.s.). Zero-scale edges are
// SKIPPED (scale is shfl-broadcast -> wave-uniform branch, divergence-free).
// NO device-scope fences (r14 lesson).
// ---------------------------------------------------------------------------
__global__ __launch_bounds__(256) void k_gather2ro(
    const unsigned short* __restrict__ hbf1, const float* __restrict__ s1m,
    const int* __restrict__ rowptr, const int* __restrict__ col,
    unsigned short* __restrict__ agg2bf, float* __restrict__ psum,
    float* __restrict__ pmax) {
  int bid = blockIdx.x;
  if (bid >= NG2BLK) {                        // ---- readout1 path ----
    int rb = bid - NG2BLK;                    // 0..1023
    int g = rb >> 4, c = rb & 15;
    int f = threadIdx.x & 127, half = threadIdx.x >> 7;
    int nbase = g * NPG + c * 64 + half;
    float sum = 0.f, mx = -1e30f;
    for (int i = 0; i < 64; i += 2) {
      int n = nbase + i;
      float sk = s1m[n];
      if (sk != 0.f) {
        float v = bf2f(hbf1[(size_t)n * NH + f]) * sk;
        sum += v;
        mx = fmaxf(mx, v);
      }
    }
    int slot = rb * 2 + half;
    psum[(size_t)slot * NH + f] = sum;
    pmax[(size_t)slot * NH + f] = mx;
    return;
  }
  // ---- gather2 path ----
  int swz = (bid & 7) * 2048 + (bid >> 3);
  int wave = threadIdx.x >> 6, lane = threadIdx.x & 63;
  int d = swz * 4 + wave;
  if (s1m[d] == 0.f) return;                  // row never consumed downstream
  int rs = rowptr[d], re = rowptr[d + 1];
  int deg = re - rs;
  int colv = 0; float sv = 0.f;
  if (lane < deg) {
    colv = col[rs + lane];
    sv = s1m[colv];
  }
  int m = deg < 64 ? deg : 64;
  float ax = 0.f, ay = 0.f;
  int nfull = m & ~3;
  int j = 0;
  for (; j < nfull; j += 4) {
    int v0 = __shfl(colv, j);
    int v1 = __shfl(colv, j + 1);
    int v2 = __shfl(colv, j + 2);
    int v3 = __shfl(colv, j + 3);
    float f0 = __shfl(sv, j);
    float f1 = __shfl(sv, j + 1);
    float f2 = __shfl(sv, j + 2);
    float f3 = __shfl(sv, j + 3);
    if (f0 != 0.f) {
      unsigned int p = *(const unsigned int*)(hbf1 + (size_t)v0 * NH + lane * 2);
      ax += bf2f(p & 0xffff) * f0; ay += bf2f(p >> 16) * f0;
    }
    if (f1 != 0.f) {
      unsigned int p = *(const unsigned int*)(hbf1 + (size_t)v1 * NH + lane * 2);
      ax += bf2f(p & 0xffff) * f1; ay += bf2f(p >> 16) * f1;
    }
    if (f2 != 0.f) {
      unsigned int p = *(const unsigned int*)(hbf1 + (size_t)v2 * NH + lane * 2);
      ax += bf2f(p & 0xffff) * f2; ay += bf2f(p >> 16) * f2;
    }
    if (f3 != 0.f) {
      unsigned int p = *(const unsigned int*)(hbf1 + (size_t)v3 * NH + lane * 2);
      ax += bf2f(p & 0xffff) * f3; ay += bf2f(p >> 16) * f3;
    }
  }
  for (; j < m; ++j) {
    int v = __shfl(colv, j);
    float f = __shfl(sv, j);
    if (f != 0.f) {
      unsigned int p = *(const unsigned int*)(hbf1 + (size_t)v * NH + lane * 2);
      ax += bf2f(p & 0xffff) * f;
      ay += bf2f(p >> 16) * f;
    }
  }
  for (int jj = rs + 64; jj < re; ++jj) {      // deg>64 fallback (≈never)
    int v = col[jj];
    float f = s1m[v];
    if (f != 0.f) {
      unsigned int p = *(const unsigned int*)(hbf1 + (size_t)v * NH + lane * 2);
      ax += bf2f(p & 0xffff) * f;
      ay += bf2f(p >> 16) * f;
    }
  }
  unsigned int packed = ((unsigned int)f2bf(ay) << 16) | (unsigned int)f2bf(ax);
  *(unsigned int*)(agg2bf + (size_t)d * NH + lane * 2) = packed;
}

// ---------------------------------------------------------------------------
// conv2 GEMM via bf16 MFMA — barrier-free, LDS-free. 2 row-groups/wave
// (W fragment reuse x2). A: agg2bf direct; root = hbf1*s1m (in-register).
// Output h2 is bf16, gated on s1m != 0. Dropped rows: finite poison in,
// masked out. D layout: col=lane&15, row=(lane>>4)*4+reg (m89). XCD-swizzled.
// ---------------------------------------------------------------------------
__global__ __launch_bounds__(256) void k_gemm2(
    const unsigned short* __restrict__ agg2bf,
    const unsigned short* __restrict__ hbf1, const float* __restrict__ s1m,
    const unsigned short* __restrict__ Wfrag, const float* __restrict__ b2,
    const float* __restrict__ p2w, unsigned short* __restrict__ h2bf,
    float* __restrict__ s2) {
  int t = threadIdx.x;
  int bid = blockIdx.x;                 // 512 blocks, 64 per XCD chunk
  int swz = (bid & 7) * 64 + (bid >> 3);
  int nb = swz * 128;
  int lane = t & 63, w = t >> 6;
  int row16 = lane & 15, kgrp = lane >> 4;
  int base = nb + 32 * w;               // wave owns rows base..base+31
  int r0 = base + row16, r1 = base + 16 + row16;

  // ---- A fragments ----
  bf16x8 a0[8], a1[8];
#pragma unroll
  for (int s = 0; s < 4; ++s) {
    int k = s * 32 + kgrp * 8;
    a0[s] = *(const bf16x8*)(agg2bf + (size_t)r0 * NH + k);
    a1[s] = *(const bf16x8*)(agg2bf + (size_t)r1 * NH + k);
  }
  {
    float sc0 = s1m[r0], sc1 = s1m[r1];
    const unsigned short* S0 = hbf1 + (size_t)r0 * NH;
    const unsigned short* S1 = hbf1 + (size_t)r1 * NH;
#pragma unroll
    for (int s = 0; s < 4; ++s) {
      int k = s * 32 + kgrp * 8;
      union { unsigned short us[8]; uint4 v; } i0, i1;
      i0.v = *(const uint4*)(S0 + k);
      i1.v = *(const uint4*)(S1 + k);
      union { unsigned short us[8]; bf16x8 v; } p, q;
#pragma unroll
      for (int u = 0; u < 8; ++u) {
        p.us[u] = f2bf(bf2f(i0.us[u]) * sc0);
        q.us[u] = f2bf(bf2f(i1.us[u]) * sc1);
      }
      a0[4 + s] = p.v;
      a1[4 + s] = q.v;
    }
  }

  // ---- MFMA: stream W fragments from L2, reuse x2 ----
  f32x4 acc0[8], acc1[8];
#pragma unroll
  for (int c = 0; c < 8; ++c) {
    acc0[c] = (f32x4){0.f, 0.f, 0.f, 0.f};
    acc1[c] = (f32x4){0.f, 0.f, 0.f, 0.f};
  }
  const bf16x8* WF = (const bf16x8*)Wfrag;
#pragma unroll
  for (int c = 0; c < 8; ++c) {
#pragma unroll
    for (int s = 0; s < 8; ++s) {
      bf16x8 wv = WF[(c * 8 + s) * 64 + lane];
      acc0[c] = __builtin_amdgcn_mfma_f32_16x16x32_bf16(a0[s], wv, acc0[c], 0, 0, 0);
      acc1[c] = __builtin_amdgcn_mfma_f32_16x16x32_bf16(a1[s], wv, acc1[c], 0, 0, 0);
    }
  }

  // ---- epilogue ----
  float bb[8], pw[8];
#pragma unroll
  for (int c = 0; c < 8; ++c) {
    bb[c] = b2[c * 16 + row16];
    pw[c] = p2w[c * 16 + row16];
  }
  float q2 = 0.f;
#pragma unroll
  for (int c = 0; c < 8; ++c) q2 += pw[c] * pw[c];
  q2 += __shfl_xor(q2, 1); q2 += __shfl_xor(q2, 2);
  q2 += __shfl_xor(q2, 4); q2 += __shfl_xor(q2, 8);
  float rnorm = rsqrtf(q2);

#pragma unroll
  for (int g2 = 0; g2 < 2; ++g2) {
    f32x4* acc = g2 ? acc1 : acc0;
    int rbase = base + g2 * 16;
    int msr[4];
#pragma unroll
    for (int r = 0; r < 4; ++r) msr[r] = (s1m[rbase + kgrp * 4 + r] != 0.f);
    float pvp[4] = {0.f, 0.f, 0.f, 0.f};
#pragma unroll
    for (int c = 0; c < 8; ++c) {
#pragma unroll
      for (int r = 0; r < 4; ++r) {
        float u = fmaxf(acc[c][r] + bb[c], 0.f);
        pvp[r] += u * pw[c];
        if (msr[r]) {                    // kept2 subset of kept1 -> safe skip
          int n = rbase + kgrp * 4 + r;
          h2bf[(size_t)n * NH + c * 16 + row16] = f2bf(u);
        }
      }
    }
#pragma unroll
    for (int r = 0; r < 4; ++r) {
      float pv = pvp[r];
      pv += __shfl_xor(pv, 1);
      pv += __shfl_xor(pv, 2);
      pv += __shfl_xor(pv, 4);
      pv += __shfl_xor(pv, 8);
      if (row16 == 0) {
        int n = rbase + kgrp * 4 + r;
        s2[n] = tanhf(pv * rnorm);
      }
    }
  }
}

// ---------------------------------------------------------------------------
// readout2 partials — gates on s2m != 0 (no kept buffer anywhere)
// ---------------------------------------------------------------------------
__global__ __launch_bounds__(256) void k_readout2(
    const unsigned short* __restrict__ h, const float* __restrict__ s2m,
    float* __restrict__ psum, float* __restrict__ pmax) {
  int g = blockIdx.x >> 4, c = blockIdx.x & 15;
  int f = threadIdx.x & 127, half = threadIdx.x >> 7;
  int nbase = g * NPG + c * 64 + half;
  float sum = 0.f, mx = -1e30f;
  for (int i = 0; i < 64; i += 2) {
    int n = nbase + i;
    float sk = s2m[n];
    if (sk != 0.f) {
      float v = bf2f(h[(size_t)n * NH + f]) * sk;
      sum += v;
      mx = fmaxf(mx, v);
    }
  }
  int slot = blockIdx.x * 2 + half;
  psum[(size_t)slot * NH + f] = sum;
  pmax[(size_t)slot * NH + f] = mx;
}

// ---------------------------------------------------------------------------
// final combine (32 partial slots per graph per layer)
// ---------------------------------------------------------------------------
__global__ __launch_bounds__(256) void k_final(
    const float* __restrict__ psum1, const float* __restrict__ pmax1,
    const float* __restrict__ psum2, const float* __restrict__ pmax2,
    float* __restrict__ out) {
  int g = blockIdx.x, t = threadIdx.x;
  if (t < 128) {
    float a = 0.f, b = 0.f;
#pragma unroll
    for (int c = 0; c < 32; ++c) {
      a += psum1[(size_t)(g * 32 + c) * NH + t];
      b += psum2[(size_t)(g * 32 + c) * NH + t];
    }
    out[(size_t)g * 256 + t] = a / (float)KP1 + b / (float)KP2;
  } else {
    int f = t - 128;
    float a = -1e30f, b = -1e30f;
#pragma unroll
    for (int c = 0; c < 32; ++c) {
      a = fmaxf(a, pmax1[(size_t)(g * 32 + c) * NH + f]);
      b = fmaxf(b, pmax2[(size_t)(g * 32 + c) * NH + f]);
    }
    out[(size_t)g * 256 + t] = a + b;
  }
}

// ---------------------------------------------------------------------------
extern "C" void kernel_launch(void* const* d_in, const int* in_sizes, int n_in,
                              void* d_out, int out_size, void* d_ws, size_t ws_size,
                              hipStream_t stream) {
  const float* x     = (const float*)d_in[0];
  const int*   eidx  = (const int*)d_in[1];
  const int*   src   = eidx;
  const int*   dst   = eidx + EDGES;
  const float* W1rel = (const float*)d_in[3];
  const float* b1    = (const float*)d_in[4];
  const float* W1rt  = (const float*)d_in[5];
  const float* p1w   = (const float*)d_in[6];
  const float* W2rel = (const float*)d_in[7];
  const float* b2    = (const float*)d_in[8];
  const float* W2rt  = (const float*)d_in[9];
  const float* p2w   = (const float*)d_in[10];
  float* out = (float*)d_out;

  // workspace layout (floats)
  float* ws = (float*)d_ws;
  size_t off = 0;
  unsigned short* hbf1   = (unsigned short*)(ws + off); off += (size_t)NODES * NH / 2;
  unsigned short* h2bf   = (unsigned short*)(ws + off); off += (size_t)NODES * NH / 2;
  unsigned short* agg2bf = (unsigned short*)(ws + off); off += (size_t)NODES * NH / 2;
  float* agg1  = ws + off; off += (size_t)NODES * FIN;
  float* s1    = ws + off; off += NODES;
  float* s2    = ws + off; off += NODES;
  float* s1m   = ws + off; off += NODES;
  float* s2m   = ws + off; off += NODES;
  float* psum1 = ws + off; off += 2048 * NH;
  float* pmax1 = ws + off; off += 2048 * NH;
  float* psum2 = ws + off; off += 2048 * NH;
  float* pmax2 = ws + off; off += 2048 * NH;
  unsigned short* Wfrag = (unsigned short*)(ws + off); off += 16384; // 64 KB
  int*   rowptr  = (int*)(ws + off); off += NODES + 1;
  int*   col     = (int*)(ws + off); off += EDGES;

  // ---- CSR build + W fragment prep (one dispatch) ----
  k_csr<<<BATCH + 4, 1024, 0, stream>>>(src, dst, rowptr, col, W2rel, W2rt,
                                        Wfrag);

  // ---- layer 1 ----
  k_gather1<<<NODES / 16, 256, 0, stream>>>(x, rowptr, col, agg1);
  k_gemm1<<<NODES / 64, 256, 0, stream>>>(x, agg1, W1rel, b1, W1rt, p1w,
                                          hbf1, s1);
  k_topk<<<BATCH, 512, 0, stream>>>(s1, nullptr, s1m, KP1);

  // ---- merged: conv2 gather + layer-1 readout ----
  k_gather2ro<<<NG2BLK + 1024, 256, 0, stream>>>(hbf1, s1m, rowptr, col,
                                                 agg2bf, psum1, pmax1);

  // ---- layer 2 ----
  k_gemm2<<<NODES / 128, 256, 0, stream>>>(agg2bf, hbf1, s1m, Wfrag,
                                           b2, p2w, h2bf, s2);
  k_topk<<<BATCH, 512, 0, stream>>>(s2, s1m, s2m, KP2);
  k_readout2<<<1024, 256, 0, stream>>>(h2bf, s2m, psum2, pmax2);
  k_final<<<BATCH, 256, 0, stream>>>(psum1, pmax1, psum2, pmax2, out);
}

// Round 19
// 149.529 us; speedup vs baseline: 1.0797x; 1.0797x over previous
//
#include <hip/hip_runtime.h>
#include <hip/hip_bf16.h>
#include <cmath>

// Problem constants
#define BATCH   64
#define NPG     1024           // nodes per graph
#define NODES   65536          // BATCH*NPG
#define EDGES   524288
#define EPG     8192           // edges per graph (contiguous slice!)
#define FIN     14
#define NH      128
#define KP1     820
#define KP2     656
#define ASTR    15             // padded LDS stride for FIN tiles (2-way, free)
#define NG2BLK  16384          // gather2 blocks in merged dispatch

typedef __attribute__((ext_vector_type(8))) short bf16x8;
typedef __attribute__((ext_vector_type(4))) float f32x4;

static __device__ __forceinline__ unsigned short f2bf(float f) {
  __hip_bfloat16 h = __float2bfloat16(f);
  return *reinterpret_cast<unsigned short*>(&h);
}
static __device__ __forceinline__ float bf2f(unsigned int u16) {
  return __uint_as_float(u16 << 16);
}

// ---------------------------------------------------------------------------
// CSR build + Wfrag prep in ONE dispatch.
// Blocks 0..63: per-graph CSR; wave-level scan (__shfl_up, 5 barriers).
// Blocks 64..67: bf16 W2 fragment table.
// NOTE (r16 lesson): x stays f32 — bf16-izing conv1 inputs perturbs s1 and
// flips top-k boundary ranks (top-k is discontinuous in the score).
// ---------------------------------------------------------------------------
__global__ __launch_bounds__(1024) void k_csr(
    const int* __restrict__ src, const int* __restrict__ dst,
    int* __restrict__ rowptr, int* __restrict__ col,
    const float* __restrict__ W2rel, const float* __restrict__ W2rt,
    unsigned short* __restrict__ Wfrag) {
  int g = blockIdx.x, t = threadIdx.x;
  if (g >= BATCH) {                           // Wfrag builder blocks
    int id = (g - BATCH) * 1024 + t;          // 0..4095
    int lane = id & 63, sg = (id >> 6) & 7, c = id >> 9;
    const float* SW = (sg < 4) ? W2rel : W2rt;
    int o = c * 16 + (lane & 15);
    int k = (sg & 3) * 32 + (lane >> 4) * 8;
    float4 f0 = *(const float4*)(SW + (size_t)o * NH + k);
    float4 f1 = *(const float4*)(SW + (size_t)o * NH + k + 4);
    union { unsigned short us[8]; uint4 v; } p;
    p.us[0] = f2bf(f0.x); p.us[1] = f2bf(f0.y);
    p.us[2] = f2bf(f0.z); p.us[3] = f2bf(f0.w);
    p.us[4] = f2bf(f1.x); p.us[5] = f2bf(f1.y);
    p.us[6] = f2bf(f1.z); p.us[7] = f2bf(f1.w);
    *(uint4*)(Wfrag + (size_t)id * 8) = p.v;
    return;
  }
  __shared__ int cnt[NPG];
  __shared__ int wsum[16];
  int ebase = g * EPG;
  cnt[t] = 0;
  __syncthreads();
  int dl[8], sl[8];
#pragma unroll
  for (int i = 0; i < 8; ++i) {
    int e = ebase + t + i * 1024;
    dl[i] = dst[e] - g * NPG;
    sl[i] = src[e];
    atomicAdd(&cnt[dl[i]], 1);
  }
  __syncthreads();
  int v = cnt[t];
  int lane = t & 63, wid = t >> 6;
  int incl = v;                               // wave-level inclusive scan
#pragma unroll
  for (int d = 1; d < 64; d <<= 1) {
    int o = __shfl_up(incl, d);
    if (lane >= d) incl += o;
  }
  if (lane == 63) wsum[wid] = incl;
  __syncthreads();
  if (wid == 0) {
    int wv = (lane < 16) ? wsum[lane] : 0;
    int wi = wv;
#pragma unroll
    for (int d = 1; d < 16; d <<= 1) {
      int o = __shfl_up(wi, d);
      if (lane >= d) wi += o;
    }
    if (lane < 16) wsum[lane] = wi - wv;      // exclusive wave base
  }
  __syncthreads();
  int excl = incl - v + wsum[wid];
  rowptr[g * NPG + t] = ebase + excl;
  if (g == 0 && t == 0) rowptr[NODES] = EDGES;
  __syncthreads();
  cnt[t] = excl;                              // becomes local cursor
  __syncthreads();
#pragma unroll
  for (int i = 0; i < 8; ++i) {
    int pos = atomicAdd(&cnt[dl[i]], 1);
    col[ebase + pos] = sl[i];
  }
}

// ---------------------------------------------------------------------------
// conv1 aggregation via CSR gather over f32 x (score-path precision).
// Col indices preloaded per 16-lane group + shfl broadcast. XCD-swizzled.
// ---------------------------------------------------------------------------
__global__ __launch_bounds__(256) void k_gather1(
    const float* __restrict__ x, const int* __restrict__ rowptr,
    const int* __restrict__ col, float* __restrict__ agg1) {
  int bid = blockIdx.x;                       // 4096 blocks, 512 per XCD chunk
  int swz = (bid & 7) * 512 + (bid >> 3);
  int t = threadIdx.x;
  int gi = t >> 4;                            // node slot in block (0..15)
  int lane = t & 63;
  int sub = lane & 15;                        // position within 16-lane group
  int gb = lane & 48;                         // group base within wave
  int su = sub < FIN ? sub : FIN - 1;         // clamped feature index
  int n = swz * 16 + gi;
  int rs = rowptr[n], re = rowptr[n + 1];
  int deg = re - rs;
  int colv = (sub < deg) ? col[rs + sub] : 0;
  int m = deg < 16 ? deg : 16;
  float acc = 0.f;
  int nfull = m & ~3;
  int j = 0;
  for (; j < nfull; j += 4) {
    int v0 = __shfl(colv, gb + j);
    int v1 = __shfl(colv, gb + j + 1);
    int v2 = __shfl(colv, gb + j + 2);
    int v3 = __shfl(colv, gb + j + 3);
    float a0 = x[(size_t)v0 * FIN + su];
    float a1 = x[(size_t)v1 * FIN + su];
    float a2 = x[(size_t)v2 * FIN + su];
    float a3 = x[(size_t)v3 * FIN + su];
    acc += a0 + a1 + a2 + a3;
  }
  for (; j < m; ++j) {
    int v = __shfl(colv, gb + j);
    acc += x[(size_t)v * FIN + su];
  }
  for (int jj = rs + 16; jj < re; ++jj) {     // deg>16 fallback (~0.3%)
    int v = col[jj];
    acc += x[(size_t)v * FIN + su];
  }
  if (sub < FIN) agg1[(size_t)n * FIN + sub] = acc;
}

// ---------------------------------------------------------------------------
// conv1 GEMM + relu + fused pool1 score; OUTPUT IS BF16 (h only; s1 is f32).
// XCD-swizzled (r19): hbf1 producer shares L2 slice with its consumers
// (gather2ro / gemm2 use the same node->XCD convention). LDS stride ASTR=15.
// ---------------------------------------------------------------------------
__global__ __launch_bounds__(256) void k_gemm1(
    const float* __restrict__ x, const float* __restrict__ agg1,
    const float* __restrict__ Wrel, const float* __restrict__ brel,
    const float* __restrict__ Wroot, const float* __restrict__ p1w,
    unsigned short* __restrict__ hbf1, float* __restrict__ s1) {
  __shared__ float As[64 * ASTR];
  __shared__ float Xs[64 * ASTR];
  __shared__ float Wl[2 * FIN][NH];
  int t = threadIdx.x;
  int bid = blockIdx.x;                       // 1024 blocks, 128 per XCD
  int swz = (bid & 7) * 128 + (bid >> 3);
  int nb = swz * 64;
  for (int i = t; i < 64 * FIN; i += 256) {
    int n = i / FIN, k = i - n * FIN;
    As[n * ASTR + k] = agg1[(size_t)nb * FIN + i];
    Xs[n * ASTR + k] = x[(size_t)nb * FIN + i];
  }
  for (int i = t; i < NH * FIN; i += 256) {
    int o = i / FIN, k = i - o * FIN;
    Wl[k][o]       = Wrel[i];
    Wl[k + FIN][o] = Wroot[i];
  }
  __syncthreads();
  int og = t & 15, ng = t >> 4, ra = ng * 4;
  float bb[8], pw[8];
#pragma unroll
  for (int j = 0; j < 4; ++j) {
    int c0 = og * 4 + j, c1 = 64 + og * 4 + j;
    bb[j] = brel[c0]; bb[j + 4] = brel[c1];
    pw[j] = p1w[c0];  pw[j + 4] = p1w[c1];
  }
  float q = 0.f;
#pragma unroll
  for (int j = 0; j < 8; ++j) q += pw[j] * pw[j];
  q += __shfl_xor(q, 1); q += __shfl_xor(q, 2);
  q += __shfl_xor(q, 4); q += __shfl_xor(q, 8);
  float rnorm = rsqrtf(q);

  float acc[4][8];
#pragma unroll
  for (int i = 0; i < 4; ++i)
#pragma unroll
    for (int j = 0; j < 8; ++j) acc[i][j] = bb[j];
#pragma unroll
  for (int k = 0; k < FIN; ++k) {
    float4 w0 = *(const float4*)&Wl[k][og * 4];
    float4 w1 = *(const float4*)&Wl[k][64 + og * 4];
#pragma unroll
    for (int i = 0; i < 4; ++i) {
      float a = As[(ra + i) * ASTR + k];
      acc[i][0] += a * w0.x; acc[i][1] += a * w0.y;
      acc[i][2] += a * w0.z; acc[i][3] += a * w0.w;
      acc[i][4] += a * w1.x; acc[i][5] += a * w1.y;
      acc[i][6] += a * w1.z; acc[i][7] += a * w1.w;
    }
  }
#pragma unroll
  for (int k = 0; k < FIN; ++k) {
    float4 w0 = *(const float4*)&Wl[FIN + k][og * 4];
    float4 w1 = *(const float4*)&Wl[FIN + k][64 + og * 4];
#pragma unroll
    for (int i = 0; i < 4; ++i) {
      float a = Xs[(ra + i) * ASTR + k];
      acc[i][0] += a * w0.x; acc[i][1] += a * w0.y;
      acc[i][2] += a * w0.z; acc[i][3] += a * w0.w;
      acc[i][4] += a * w1.x; acc[i][5] += a * w1.y;
      acc[i][6] += a * w1.z; acc[i][7] += a * w1.w;
    }
  }
#pragma unroll
  for (int i = 0; i < 4; ++i) {
    int n = nb + ra + i;
    float pv = 0.f;
    union { unsigned short us[4]; uint2 v; } o0, o1;
#pragma unroll
    for (int j = 0; j < 4; ++j) {
      float v0 = fmaxf(acc[i][j], 0.f);
      float v1 = fmaxf(acc[i][4 + j], 0.f);
      pv += v0 * pw[j] + v1 * pw[4 + j];
      o0.us[j] = f2bf(v0);
      o1.us[j] = f2bf(v1);
    }
    *(uint2*)(hbf1 + (size_t)n * NH + og * 4) = o0.v;
    *(uint2*)(hbf1 + (size_t)n * NH + 64 + og * 4) = o1.v;
    pv += __shfl_xor(pv, 1);
    pv += __shfl_xor(pv, 2);
    pv += __shfl_xor(pv, 4);
    pv += __shfl_xor(pv, 8);
    if (og == 0) s1[n] = tanhf(pv * rnorm);
  }
}

// ---------------------------------------------------------------------------
// exact per-graph top-K via 4-level RADIX SELECT (replaces bitonic sort):
// finds the exact K-th largest monotone-ordered key T in 4 histogram passes
// (~12 barriers, no LDS data shuffling), then sm_out[n] = (ord>=T)?score:0
// with fully coalesced writes. Selection is bit-identical to a full sort
// (scores are distinct floats). Masked nodes get ord=0 < any real score.
// ---------------------------------------------------------------------------
__global__ __launch_bounds__(512) void k_topk(
    const float* __restrict__ score, const float* __restrict__ mask_sm,
    float* __restrict__ sm_out, int K) {
  __shared__ int hist[256];
  __shared__ int sh_bin, sh_base;
  int t = threadIdx.x, g = blockIdx.x;
  unsigned int ordv[2];
  float sval[2];
#pragma unroll
  for (int i = 0; i < 2; ++i) {
    int n = g * NPG + t + i * 512;
    float s = score[n];
    sval[i] = s;
    unsigned int u = __float_as_uint(s);
    unsigned int ord = (u & 0x80000000u) ? ~u : (u | 0x80000000u);
    if (mask_sm && mask_sm[n] == 0.f) ord = 0u;
    ordv[i] = ord;
  }
  unsigned int pref = 0u;
  int Krem = K;
  for (int lev = 3; lev >= 0; --lev) {
    int sh = lev * 8;
    unsigned int maskHigh = (lev == 3) ? 0u : (0xFFFFFFFFu << (sh + 8));
    if (t < 256) hist[t] = 0;
    __syncthreads();
#pragma unroll
    for (int i = 0; i < 2; ++i)
      if ((ordv[i] & maskHigh) == pref)
        atomicAdd(&hist[(ordv[i] >> sh) & 0xFF], 1);
    __syncthreads();
    if (t < 64) {                            // single-wave suffix scan
      int b3 = 255 - 4 * t;                  // lane owns bins b3..b3-3 (desc)
      int h0 = hist[b3], h1 = hist[b3 - 1];
      int h2 = hist[b3 - 2], h3 = hist[b3 - 3];
      int lsum = h0 + h1 + h2 + h3;
      int run = lsum;
#pragma unroll
      for (int d = 1; d < 64; d <<= 1) {
        int o = __shfl_up(run, d);
        if (t >= d) run += o;
      }
      int excl = run - lsum;                 // count in strictly-higher bins
      int c0 = excl + h0, c1 = c0 + h1, c2 = c1 + h2;
      if (excl < Krem && Krem <= c0)           { sh_bin = b3;     sh_base = excl; }
      else if (c0 < Krem && Krem <= c1)        { sh_bin = b3 - 1; sh_base = c0; }
      else if (c1 < Krem && Krem <= c2)        { sh_bin = b3 - 2; sh_base = c1; }
      else if (c2 < Krem && Krem <= c2 + h3)   { sh_bin = b3 - 3; sh_base = c2; }
    }
    __syncthreads();
    pref |= ((unsigned int)sh_bin) << sh;
    Krem -= sh_base;
    __syncthreads();
  }
  // pref == exact K-th largest ord; exactly K elements have ord >= pref
#pragma unroll
  for (int i = 0; i < 2; ++i) {
    int n = g * NPG + t + i * 512;
    sm_out[n] = (ordv[i] >= pref) ? sval[i] : 0.f;
  }
}

// ---------------------------------------------------------------------------
// MERGED dispatch: gather2 (blocks 0..16383) + readout1 (blocks 16384..17407).
// All gating on s1m != 0. Zero-scale edges skipped (wave-uniform branch).
// NO device-scope fences (r14 lesson).
// ---------------------------------------------------------------------------
__global__ __launch_bounds__(256) void k_gather2ro(
    const unsigned short* __restrict__ hbf1, const float* __restrict__ s1m,
    const int* __restrict__ rowptr, const int* __restrict__ col,
    unsigned short* __restrict__ agg2bf, float* __restrict__ psum,
    float* __restrict__ pmax) {
  int bid = blockIdx.x;
  if (bid >= NG2BLK) {                        // ---- readout1 path ----
    int rb = bid - NG2BLK;                    // 0..1023
    int g = rb >> 4, c = rb & 15;
    int f = threadIdx.x & 127, half = threadIdx.x >> 7;
    int nbase = g * NPG + c * 64 + half;
    float sum = 0.f, mx = -1e30f;
    for (int i = 0; i < 64; i += 2) {
      int n = nbase + i;
      float sk = s1m[n];
      if (sk != 0.f) {
        float v = bf2f(hbf1[(size_t)n * NH + f]) * sk;
        sum += v;
        mx = fmaxf(mx, v);
      }
    }
    int slot = rb * 2 + half;
    psum[(size_t)slot * NH + f] = sum;
    pmax[(size_t)slot * NH + f] = mx;
    return;
  }
  // ---- gather2 path ----
  int swz = (bid & 7) * 2048 + (bid >> 3);
  int wave = threadIdx.x >> 6, lane = threadIdx.x & 63;
  int d = swz * 4 + wave;
  if (s1m[d] == 0.f) return;                  // row never consumed downstream
  int rs = rowptr[d], re = rowptr[d + 1];
  int deg = re - rs;
  int colv = 0; float sv = 0.f;
  if (lane < deg) {
    colv = col[rs + lane];
    sv = s1m[colv];
  }
  int m = deg < 64 ? deg : 64;
  float ax = 0.f, ay = 0.f;
  int nfull = m & ~3;
  int j = 0;
  for (; j < nfull; j += 4) {
    int v0 = __shfl(colv, j);
    int v1 = __shfl(colv, j + 1);
    int v2 = __shfl(colv, j + 2);
    int v3 = __shfl(colv, j + 3);
    float f0 = __shfl(sv, j);
    float f1 = __shfl(sv, j + 1);
    float f2 = __shfl(sv, j + 2);
    float f3 = __shfl(sv, j + 3);
    if (f0 != 0.f) {
      unsigned int p = *(const unsigned int*)(hbf1 + (size_t)v0 * NH + lane * 2);
      ax += bf2f(p & 0xffff) * f0; ay += bf2f(p >> 16) * f0;
    }
    if (f1 != 0.f) {
      unsigned int p = *(const unsigned int*)(hbf1 + (size_t)v1 * NH + lane * 2);
      ax += bf2f(p & 0xffff) * f1; ay += bf2f(p >> 16) * f1;
    }
    if (f2 != 0.f) {
      unsigned int p = *(const unsigned int*)(hbf1 + (size_t)v2 * NH + lane * 2);
      ax += bf2f(p & 0xffff) * f2; ay += bf2f(p >> 16) * f2;
    }
    if (f3 != 0.f) {
      unsigned int p = *(const unsigned int*)(hbf1 + (size_t)v3 * NH + lane * 2);
      ax += bf2f(p & 0xffff) * f3; ay += bf2f(p >> 16) * f3;
    }
  }
  for (; j < m; ++j) {
    int v = __shfl(colv, j);
    float f = __shfl(sv, j);
    if (f != 0.f) {
      unsigned int p = *(const unsigned int*)(hbf1 + (size_t)v * NH + lane * 2);
      ax += bf2f(p & 0xffff) * f;
      ay += bf2f(p >> 16) * f;
    }
  }
  for (int jj = rs + 64; jj < re; ++jj) {      // deg>64 fallback (≈never)
    int v = col[jj];
    float f = s1m[v];
    if (f != 0.f) {
      unsigned int p = *(const unsigned int*)(hbf1 + (size_t)v * NH + lane * 2);
      ax += bf2f(p & 0xffff) * f;
      ay += bf2f(p >> 16) * f;
    }
  }
  unsigned int packed = ((unsigned int)f2bf(ay) << 16) | (unsigned int)f2bf(ax);
  *(unsigned int*)(agg2bf + (size_t)d * NH + lane * 2) = packed;
}

// ---------------------------------------------------------------------------
// conv2 GEMM via bf16 MFMA — barrier-free, LDS-free. 2 row-groups/wave
// (W fragment reuse x2). A: agg2bf direct; root = hbf1*s1m (in-register).
// Output h2 is bf16, gated on s1m != 0. D layout: col=lane&15,
// row=(lane>>4)*4+reg (m89). XCD-swizzled.
// ---------------------------------------------------------------------------
__global__ __launch_bounds__(256) void k_gemm2(
    const unsigned short* __restrict__ agg2bf,
    const unsigned short* __restrict__ hbf1, const float* __restrict__ s1m,
    const unsigned short* __restrict__ Wfrag, const float* __restrict__ b2,
    const float* __restrict__ p2w, unsigned short* __restrict__ h2bf,
    float* __restrict__ s2) {
  int t = threadIdx.x;
  int bid = blockIdx.x;                 // 512 blocks, 64 per XCD chunk
  int swz = (bid & 7) * 64 + (bid >> 3);
  int nb = swz * 128;
  int lane = t & 63, w = t >> 6;
  int row16 = lane & 15, kgrp = lane >> 4;
  int base = nb + 32 * w;               // wave owns rows base..base+31
  int r0 = base + row16, r1 = base + 16 + row16;

  // ---- A fragments ----
  bf16x8 a0[8], a1[8];
#pragma unroll
  for (int s = 0; s < 4; ++s) {
    int k = s * 32 + kgrp * 8;
    a0[s] = *(const bf16x8*)(agg2bf + (size_t)r0 * NH + k);
    a1[s] = *(const bf16x8*)(agg2bf + (size_t)r1 * NH + k);
  }
  {
    float sc0 = s1m[r0], sc1 = s1m[r1];
    const unsigned short* S0 = hbf1 + (size_t)r0 * NH;
    const unsigned short* S1 = hbf1 + (size_t)r1 * NH;
#pragma unroll
    for (int s = 0; s < 4; ++s) {
      int k = s * 32 + kgrp * 8;
      union { unsigned short us[8]; uint4 v; } i0, i1;
      i0.v = *(const uint4*)(S0 + k);
      i1.v = *(const uint4*)(S1 + k);
      union { unsigned short us[8]; bf16x8 v; } p, q;
#pragma unroll
      for (int u = 0; u < 8; ++u) {
        p.us[u] = f2bf(bf2f(i0.us[u]) * sc0);
        q.us[u] = f2bf(bf2f(i1.us[u]) * sc1);
      }
      a0[4 + s] = p.v;
      a1[4 + s] = q.v;
    }
  }

  // ---- MFMA: stream W fragments from L2, reuse x2 ----
  f32x4 acc0[8], acc1[8];
#pragma unroll
  for (int c = 0; c < 8; ++c) {
    acc0[c] = (f32x4){0.f, 0.f, 0.f, 0.f};
    acc1[c] = (f32x4){0.f, 0.f, 0.f, 0.f};
  }
  const bf16x8* WF = (const bf16x8*)Wfrag;
#pragma unroll
  for (int c = 0; c < 8; ++c) {
#pragma unroll
    for (int s = 0; s < 8; ++s) {
      bf16x8 wv = WF[(c * 8 + s) * 64 + lane];
      acc0[c] = __builtin_amdgcn_mfma_f32_16x16x32_bf16(a0[s], wv, acc0[c], 0, 0, 0);
      acc1[c] = __builtin_amdgcn_mfma_f32_16x16x32_bf16(a1[s], wv, acc1[c], 0, 0, 0);
    }
  }

  // ---- epilogue ----
  float bb[8], pw[8];
#pragma unroll
  for (int c = 0; c < 8; ++c) {
    bb[c] = b2[c * 16 + row16];
    pw[c] = p2w[c * 16 + row16];
  }
  float q2 = 0.f;
#pragma unroll
  for (int c = 0; c < 8; ++c) q2 += pw[c] * pw[c];
  q2 += __shfl_xor(q2, 1); q2 += __shfl_xor(q2, 2);
  q2 += __shfl_xor(q2, 4); q2 += __shfl_xor(q2, 8);
  float rnorm = rsqrtf(q2);

#pragma unroll
  for (int g2 = 0; g2 < 2; ++g2) {
    f32x4* acc = g2 ? acc1 : acc0;
    int rbase = base + g2 * 16;
    int msr[4];
#pragma unroll
    for (int r = 0; r < 4; ++r) msr[r] = (s1m[rbase + kgrp * 4 + r] != 0.f);
    float pvp[4] = {0.f, 0.f, 0.f, 0.f};
#pragma unroll
    for (int c = 0; c < 8; ++c) {
#pragma unroll
      for (int r = 0; r < 4; ++r) {
        float u = fmaxf(acc[c][r] + bb[c], 0.f);
        pvp[r] += u * pw[c];
        if (msr[r]) {                    // kept2 subset of kept1 -> safe skip
          int n = rbase + kgrp * 4 + r;
          h2bf[(size_t)n * NH + c * 16 + row16] = f2bf(u);
        }
      }
    }
#pragma unroll
    for (int r = 0; r < 4; ++r) {
      float pv = pvp[r];
      pv += __shfl_xor(pv, 1);
      pv += __shfl_xor(pv, 2);
      pv += __shfl_xor(pv, 4);
      pv += __shfl_xor(pv, 8);
      if (row16 == 0) {
        int n = rbase + kgrp * 4 + r;
        s2[n] = tanhf(pv * rnorm);
      }
    }
  }
}

// ---------------------------------------------------------------------------
// readout2 partials — gates on s2m != 0 (no kept buffer anywhere)
// ---------------------------------------------------------------------------
__global__ __launch_bounds__(256) void k_readout2(
    const unsigned short* __restrict__ h, const float* __restrict__ s2m,
    float* __restrict__ psum, float* __restrict__ pmax) {
  int g = blockIdx.x >> 4, c = blockIdx.x & 15;
  int f = threadIdx.x & 127, half = threadIdx.x >> 7;
  int nbase = g * NPG + c * 64 + half;
  float sum = 0.f, mx = -1e30f;
  for (int i = 0; i < 64; i += 2) {
    int n = nbase + i;
    float sk = s2m[n];
    if (sk != 0.f) {
      float v = bf2f(h[(size_t)n * NH + f]) * sk;
      sum += v;
      mx = fmaxf(mx, v);
    }
  }
  int slot = blockIdx.x * 2 + half;
  psum[(size_t)slot * NH + f] = sum;
  pmax[(size_t)slot * NH + f] = mx;
}

// ---------------------------------------------------------------------------
// final combine (32 partial slots per graph per layer)
// ---------------------------------------------------------------------------
__global__ __launch_bounds__(256) void k_final(
    const float* __restrict__ psum1, const float* __restrict__ pmax1,
    const float* __restrict__ psum2, const float* __restrict__ pmax2,
    float* __restrict__ out) {
  int g = blockIdx.x, t = threadIdx.x;
  if (t < 128) {
    float a = 0.f, b = 0.f;
#pragma unroll
    for (int c = 0; c < 32; ++c) {
      a += psum1[(size_t)(g * 32 + c) * NH + t];
      b += psum2[(size_t)(g * 32 + c) * NH + t];
    }
    out[(size_t)g * 256 + t] = a / (float)KP1 + b / (float)KP2;
  } else {
    int f = t - 128;
    float a = -1e30f, b = -1e30f;
#pragma unroll
    for (int c = 0; c < 32; ++c) {
      a = fmaxf(a, pmax1[(size_t)(g * 32 + c) * NH + f]);
      b = fmaxf(b, pmax2[(size_t)(g * 32 + c) * NH + f]);
    }
    out[(size_t)g * 256 + t] = a + b;
  }
}

// ---------------------------------------------------------------------------
extern "C" void kernel_launch(void* const* d_in, const int* in_sizes, int n_in,
                              void* d_out, int out_size, void* d_ws, size_t ws_size,
                              hipStream_t stream) {
  const float* x     = (const float*)d_in[0];
  const int*   eidx  = (const int*)d_in[1];
  const int*   src   = eidx;
  const int*   dst   = eidx + EDGES;
  const float* W1rel = (const float*)d_in[3];
  const float* b1    = (const float*)d_in[4];
  const float* W1rt  = (const float*)d_in[5];
  const float* p1w   = (const float*)d_in[6];
  const float* W2rel = (const float*)d_in[7];
  const float* b2    = (const float*)d_in[8];
  const float* W2rt  = (const float*)d_in[9];
  const float* p2w   = (const float*)d_in[10];
  float* out = (float*)d_out;

  // workspace layout (floats)
  float* ws = (float*)d_ws;
  size_t off = 0;
  unsigned short* hbf1   = (unsigned short*)(ws + off); off += (size_t)NODES * NH / 2;
  unsigned short* h2bf   = (unsigned short*)(ws + off); off += (size_t)NODES * NH / 2;
  unsigned short* agg2bf = (unsigned short*)(ws + off); off += (size_t)NODES * NH / 2;
  float* agg1  = ws + off; off += (size_t)NODES * FIN;
  float* s1    = ws + off; off += NODES;
  float* s2    = ws + off; off += NODES;
  float* s1m   = ws + off; off += NODES;
  float* s2m   = ws + off; off += NODES;
  float* psum1 = ws + off; off += 2048 * NH;
  float* pmax1 = ws + off; off += 2048 * NH;
  float* psum2 = ws + off; off += 2048 * NH;
  float* pmax2 = ws + off; off += 2048 * NH;
  unsigned short* Wfrag = (unsigned short*)(ws + off); off += 16384; // 64 KB
  int*   rowptr  = (int*)(ws + off); off += NODES + 1;
  int*   col     = (int*)(ws + off); off += EDGES;

  // ---- CSR build + W fragment prep (one dispatch) ----
  k_csr<<<BATCH + 4, 1024, 0, stream>>>(src, dst, rowptr, col, W2rel, W2rt,
                                        Wfrag);

  // ---- layer 1 ----
  k_gather1<<<NODES / 16, 256, 0, stream>>>(x, rowptr, col, agg1);
  k_gemm1<<<NODES / 64, 256, 0, stream>>>(x, agg1, W1rel, b1, W1rt, p1w,
                                          hbf1, s1);
  k_topk<<<BATCH, 512, 0, stream>>>(s1, nullptr, s1m, KP1);

  // ---- merged: conv2 gather + layer-1 readout ----
  k_gather2ro<<<NG2BLK + 1024, 256, 0, stream>>>(hbf1, s1m, rowptr, col,
                                                 agg2bf, psum1, pmax1);

  // ---- layer 2 ----
  k_gemm2<<<NODES / 128, 256, 0, stream>>>(agg2bf, hbf1, s1m, Wfrag,
                                           b2, p2w, h2bf, s2);
  k_topk<<<BATCH, 512, 0, stream>>>(s2, s1m, s2m, KP2);
  k_readout2<<<1024, 256, 0, stream>>>(h2bf, s2m, psum2, pmax2);
  k_final<<<BATCH, 256, 0, stream>>>(psum1, pmax1, psum2, pmax2, out);
}

// Round 20
// 140.795 us; speedup vs baseline: 1.1467x; 1.0620x over previous
//
#include <hip/hip_runtime.h>
#include <hip/hip_bf16.h>
#include <cmath>

// Problem constants
#define BATCH   64
#define NPG     1024           // nodes per graph
#define NODES   65536          // BATCH*NPG
#define EDGES   524288
#define EPG     8192           // edges per graph (contiguous slice!)
#define FIN     14
#define NH      128
#define KP1     820
#define KP2     656
#define ASTR    15             // padded LDS stride for FIN tiles (2-way, free)
#define NG2BLK  16384          // gather2 blocks in merged dispatch

typedef __attribute__((ext_vector_type(8))) short bf16x8;
typedef __attribute__((ext_vector_type(4))) float f32x4;

static __device__ __forceinline__ unsigned short f2bf(float f) {
  __hip_bfloat16 h = __float2bfloat16(f);
  return *reinterpret_cast<unsigned short*>(&h);
}
static __device__ __forceinline__ float bf2f(unsigned int u16) {
  return __uint_as_float(u16 << 16);
}

// ---------------------------------------------------------------------------
// CSR build + Wfrag prep in ONE dispatch.
// Blocks 0..63: per-graph CSR; wave-level scan (__shfl_up, 5 barriers).
// Blocks 64..67: bf16 W2 fragment table.
// NOTE (r16 lesson): x stays f32 — bf16-izing conv1 inputs perturbs s1 and
// flips top-k boundary ranks (top-k is discontinuous in the score).
// ---------------------------------------------------------------------------
__global__ __launch_bounds__(1024) void k_csr(
    const int* __restrict__ src, const int* __restrict__ dst,
    int* __restrict__ rowptr, int* __restrict__ col,
    const float* __restrict__ W2rel, const float* __restrict__ W2rt,
    unsigned short* __restrict__ Wfrag) {
  int g = blockIdx.x, t = threadIdx.x;
  if (g >= BATCH) {                           // Wfrag builder blocks
    int id = (g - BATCH) * 1024 + t;          // 0..4095
    int lane = id & 63, sg = (id >> 6) & 7, c = id >> 9;
    const float* SW = (sg < 4) ? W2rel : W2rt;
    int o = c * 16 + (lane & 15);
    int k = (sg & 3) * 32 + (lane >> 4) * 8;
    float4 f0 = *(const float4*)(SW + (size_t)o * NH + k);
    float4 f1 = *(const float4*)(SW + (size_t)o * NH + k + 4);
    union { unsigned short us[8]; uint4 v; } p;
    p.us[0] = f2bf(f0.x); p.us[1] = f2bf(f0.y);
    p.us[2] = f2bf(f0.z); p.us[3] = f2bf(f0.w);
    p.us[4] = f2bf(f1.x); p.us[5] = f2bf(f1.y);
    p.us[6] = f2bf(f1.z); p.us[7] = f2bf(f1.w);
    *(uint4*)(Wfrag + (size_t)id * 8) = p.v;
    return;
  }
  __shared__ int cnt[NPG];
  __shared__ int wsum[16];
  int ebase = g * EPG;
  cnt[t] = 0;
  __syncthreads();
  int dl[8], sl[8];
#pragma unroll
  for (int i = 0; i < 8; ++i) {
    int e = ebase + t + i * 1024;
    dl[i] = dst[e] - g * NPG;
    sl[i] = src[e];
    atomicAdd(&cnt[dl[i]], 1);
  }
  __syncthreads();
  int v = cnt[t];
  int lane = t & 63, wid = t >> 6;
  int incl = v;                               // wave-level inclusive scan
#pragma unroll
  for (int d = 1; d < 64; d <<= 1) {
    int o = __shfl_up(incl, d);
    if (lane >= d) incl += o;
  }
  if (lane == 63) wsum[wid] = incl;
  __syncthreads();
  if (wid == 0) {
    int wv = (lane < 16) ? wsum[lane] : 0;
    int wi = wv;
#pragma unroll
    for (int d = 1; d < 16; d <<= 1) {
      int o = __shfl_up(wi, d);
      if (lane >= d) wi += o;
    }
    if (lane < 16) wsum[lane] = wi - wv;      // exclusive wave base
  }
  __syncthreads();
  int excl = incl - v + wsum[wid];
  rowptr[g * NPG + t] = ebase + excl;
  if (g == 0 && t == 0) rowptr[NODES] = EDGES;
  __syncthreads();
  cnt[t] = excl;                              // becomes local cursor
  __syncthreads();
#pragma unroll
  for (int i = 0; i < 8; ++i) {
    int pos = atomicAdd(&cnt[dl[i]], 1);
    col[ebase + pos] = sl[i];
  }
}

// ---------------------------------------------------------------------------
// conv1 aggregation via CSR gather over f32 x (score-path precision).
// Col indices preloaded per 16-lane group + shfl broadcast. XCD-swizzled.
// ---------------------------------------------------------------------------
__global__ __launch_bounds__(256) void k_gather1(
    const float* __restrict__ x, const int* __restrict__ rowptr,
    const int* __restrict__ col, float* __restrict__ agg1) {
  int bid = blockIdx.x;                       // 4096 blocks, 512 per XCD chunk
  int swz = (bid & 7) * 512 + (bid >> 3);
  int t = threadIdx.x;
  int gi = t >> 4;                            // node slot in block (0..15)
  int lane = t & 63;
  int sub = lane & 15;                        // position within 16-lane group
  int gb = lane & 48;                         // group base within wave
  int su = sub < FIN ? sub : FIN - 1;         // clamped feature index
  int n = swz * 16 + gi;
  int rs = rowptr[n], re = rowptr[n + 1];
  int deg = re - rs;
  int colv = (sub < deg) ? col[rs + sub] : 0;
  int m = deg < 16 ? deg : 16;
  float acc = 0.f;
  int nfull = m & ~3;
  int j = 0;
  for (; j < nfull; j += 4) {
    int v0 = __shfl(colv, gb + j);
    int v1 = __shfl(colv, gb + j + 1);
    int v2 = __shfl(colv, gb + j + 2);
    int v3 = __shfl(colv, gb + j + 3);
    float a0 = x[(size_t)v0 * FIN + su];
    float a1 = x[(size_t)v1 * FIN + su];
    float a2 = x[(size_t)v2 * FIN + su];
    float a3 = x[(size_t)v3 * FIN + su];
    acc += a0 + a1 + a2 + a3;
  }
  for (; j < m; ++j) {
    int v = __shfl(colv, gb + j);
    acc += x[(size_t)v * FIN + su];
  }
  for (int jj = rs + 16; jj < re; ++jj) {     // deg>16 fallback (~0.3%)
    int v = col[jj];
    acc += x[(size_t)v * FIN + su];
  }
  if (sub < FIN) agg1[(size_t)n * FIN + sub] = acc;
}

// ---------------------------------------------------------------------------
// conv1 GEMM + relu + fused pool1 score; OUTPUT IS BF16 (h only; s1 is f32).
// XCD-swizzled: hbf1 producer shares L2 slice with consumers. ASTR=15.
// ---------------------------------------------------------------------------
__global__ __launch_bounds__(256) void k_gemm1(
    const float* __restrict__ x, const float* __restrict__ agg1,
    const float* __restrict__ Wrel, const float* __restrict__ brel,
    const float* __restrict__ Wroot, const float* __restrict__ p1w,
    unsigned short* __restrict__ hbf1, float* __restrict__ s1) {
  __shared__ float As[64 * ASTR];
  __shared__ float Xs[64 * ASTR];
  __shared__ float Wl[2 * FIN][NH];
  int t = threadIdx.x;
  int bid = blockIdx.x;                       // 1024 blocks, 128 per XCD
  int swz = (bid & 7) * 128 + (bid >> 3);
  int nb = swz * 64;
  for (int i = t; i < 64 * FIN; i += 256) {
    int n = i / FIN, k = i - n * FIN;
    As[n * ASTR + k] = agg1[(size_t)nb * FIN + i];
    Xs[n * ASTR + k] = x[(size_t)nb * FIN + i];
  }
  for (int i = t; i < NH * FIN; i += 256) {
    int o = i / FIN, k = i - o * FIN;
    Wl[k][o]       = Wrel[i];
    Wl[k + FIN][o] = Wroot[i];
  }
  __syncthreads();
  int og = t & 15, ng = t >> 4, ra = ng * 4;
  float bb[8], pw[8];
#pragma unroll
  for (int j = 0; j < 4; ++j) {
    int c0 = og * 4 + j, c1 = 64 + og * 4 + j;
    bb[j] = brel[c0]; bb[j + 4] = brel[c1];
    pw[j] = p1w[c0];  pw[j + 4] = p1w[c1];
  }
  float q = 0.f;
#pragma unroll
  for (int j = 0; j < 8; ++j) q += pw[j] * pw[j];
  q += __shfl_xor(q, 1); q += __shfl_xor(q, 2);
  q += __shfl_xor(q, 4); q += __shfl_xor(q, 8);
  float rnorm = rsqrtf(q);

  float acc[4][8];
#pragma unroll
  for (int i = 0; i < 4; ++i)
#pragma unroll
    for (int j = 0; j < 8; ++j) acc[i][j] = bb[j];
#pragma unroll
  for (int k = 0; k < FIN; ++k) {
    float4 w0 = *(const float4*)&Wl[k][og * 4];
    float4 w1 = *(const float4*)&Wl[k][64 + og * 4];
#pragma unroll
    for (int i = 0; i < 4; ++i) {
      float a = As[(ra + i) * ASTR + k];
      acc[i][0] += a * w0.x; acc[i][1] += a * w0.y;
      acc[i][2] += a * w0.z; acc[i][3] += a * w0.w;
      acc[i][4] += a * w1.x; acc[i][5] += a * w1.y;
      acc[i][6] += a * w1.z; acc[i][7] += a * w1.w;
    }
  }
#pragma unroll
  for (int k = 0; k < FIN; ++k) {
    float4 w0 = *(const float4*)&Wl[FIN + k][og * 4];
    float4 w1 = *(const float4*)&Wl[FIN + k][64 + og * 4];
#pragma unroll
    for (int i = 0; i < 4; ++i) {
      float a = Xs[(ra + i) * ASTR + k];
      acc[i][0] += a * w0.x; acc[i][1] += a * w0.y;
      acc[i][2] += a * w0.z; acc[i][3] += a * w0.w;
      acc[i][4] += a * w1.x; acc[i][5] += a * w1.y;
      acc[i][6] += a * w1.z; acc[i][7] += a * w1.w;
    }
  }
#pragma unroll
  for (int i = 0; i < 4; ++i) {
    int n = nb + ra + i;
    float pv = 0.f;
    union { unsigned short us[4]; uint2 v; } o0, o1;
#pragma unroll
    for (int j = 0; j < 4; ++j) {
      float v0 = fmaxf(acc[i][j], 0.f);
      float v1 = fmaxf(acc[i][4 + j], 0.f);
      pv += v0 * pw[j] + v1 * pw[4 + j];
      o0.us[j] = f2bf(v0);
      o1.us[j] = f2bf(v1);
    }
    *(uint2*)(hbf1 + (size_t)n * NH + og * 4) = o0.v;
    *(uint2*)(hbf1 + (size_t)n * NH + 64 + og * 4) = o1.v;
    pv += __shfl_xor(pv, 1);
    pv += __shfl_xor(pv, 2);
    pv += __shfl_xor(pv, 4);
    pv += __shfl_xor(pv, 8);
    if (og == 0) s1[n] = tanhf(pv * rnorm);
  }
}

// ---------------------------------------------------------------------------
// exact per-graph top-K via 4-level RADIX SELECT: exact K-th largest ord in
// 4 histogram passes, coalesced sm_out writes. (Score ties at the boundary
// keep all tied nodes — measure-zero effect, within threshold.)
// ---------------------------------------------------------------------------
__global__ __launch_bounds__(512) void k_topk(
    const float* __restrict__ score, const float* __restrict__ mask_sm,
    float* __restrict__ sm_out, int K) {
  __shared__ int hist[256];
  __shared__ int sh_bin, sh_base;
  int t = threadIdx.x, g = blockIdx.x;
  unsigned int ordv[2];
  float sval[2];
#pragma unroll
  for (int i = 0; i < 2; ++i) {
    int n = g * NPG + t + i * 512;
    float s = score[n];
    sval[i] = s;
    unsigned int u = __float_as_uint(s);
    unsigned int ord = (u & 0x80000000u) ? ~u : (u | 0x80000000u);
    if (mask_sm && mask_sm[n] == 0.f) ord = 0u;
    ordv[i] = ord;
  }
  unsigned int pref = 0u;
  int Krem = K;
  for (int lev = 3; lev >= 0; --lev) {
    int sh = lev * 8;
    unsigned int maskHigh = (lev == 3) ? 0u : (0xFFFFFFFFu << (sh + 8));
    if (t < 256) hist[t] = 0;
    __syncthreads();
#pragma unroll
    for (int i = 0; i < 2; ++i)
      if ((ordv[i] & maskHigh) == pref)
        atomicAdd(&hist[(ordv[i] >> sh) & 0xFF], 1);
    __syncthreads();
    if (t < 64) {                            // single-wave suffix scan
      int b3 = 255 - 4 * t;                  // lane owns bins b3..b3-3 (desc)
      int h0 = hist[b3], h1 = hist[b3 - 1];
      int h2 = hist[b3 - 2], h3 = hist[b3 - 3];
      int lsum = h0 + h1 + h2 + h3;
      int run = lsum;
#pragma unroll
      for (int d = 1; d < 64; d <<= 1) {
        int o = __shfl_up(run, d);
        if (t >= d) run += o;
      }
      int excl = run - lsum;                 // count in strictly-higher bins
      int c0 = excl + h0, c1 = c0 + h1, c2 = c1 + h2;
      if (excl < Krem && Krem <= c0)           { sh_bin = b3;     sh_base = excl; }
      else if (c0 < Krem && Krem <= c1)        { sh_bin = b3 - 1; sh_base = c0; }
      else if (c1 < Krem && Krem <= c2)        { sh_bin = b3 - 2; sh_base = c1; }
      else if (c2 < Krem && Krem <= c2 + h3)   { sh_bin = b3 - 3; sh_base = c2; }
    }
    __syncthreads();
    pref |= ((unsigned int)sh_bin) << sh;
    Krem -= sh_base;
    __syncthreads();
  }
#pragma unroll
  for (int i = 0; i < 2; ++i) {
    int n = g * NPG + t + i * 512;
    sm_out[n] = (ordv[i] >= pref) ? sval[i] : 0.f;
  }
}

// ---------------------------------------------------------------------------
// MERGED dispatch: gather2 (blocks 0..16383) + readout1 (blocks 16384..17407).
// All gating on s1m != 0. Zero-scale edges skipped (wave-uniform branch).
// NO device-scope fences (r14 lesson).
// ---------------------------------------------------------------------------
__global__ __launch_bounds__(256) void k_gather2ro(
    const unsigned short* __restrict__ hbf1, const float* __restrict__ s1m,
    const int* __restrict__ rowptr, const int* __restrict__ col,
    unsigned short* __restrict__ agg2bf, float* __restrict__ psum,
    float* __restrict__ pmax) {
  int bid = blockIdx.x;
  if (bid >= NG2BLK) {                        // ---- readout1 path ----
    int rb = bid - NG2BLK;                    // 0..1023
    int g = rb >> 4, c = rb & 15;
    int f = threadIdx.x & 127, half = threadIdx.x >> 7;
    int nbase = g * NPG + c * 64 + half;
    float sum = 0.f, mx = -1e30f;
    for (int i = 0; i < 64; i += 2) {
      int n = nbase + i;
      float sk = s1m[n];
      if (sk != 0.f) {
        float v = bf2f(hbf1[(size_t)n * NH + f]) * sk;
        sum += v;
        mx = fmaxf(mx, v);
      }
    }
    int slot = rb * 2 + half;
    psum[(size_t)slot * NH + f] = sum;
    pmax[(size_t)slot * NH + f] = mx;
    return;
  }
  // ---- gather2 path ----
  int swz = (bid & 7) * 2048 + (bid >> 3);
  int wave = threadIdx.x >> 6, lane = threadIdx.x & 63;
  int d = swz * 4 + wave;
  if (s1m[d] == 0.f) return;                  // row never consumed downstream
  int rs = rowptr[d], re = rowptr[d + 1];
  int deg = re - rs;
  int colv = 0; float sv = 0.f;
  if (lane < deg) {
    colv = col[rs + lane];
    sv = s1m[colv];
  }
  int m = deg < 64 ? deg : 64;
  float ax = 0.f, ay = 0.f;
  int nfull = m & ~3;
  int j = 0;
  for (; j < nfull; j += 4) {
    int v0 = __shfl(colv, j);
    int v1 = __shfl(colv, j + 1);
    int v2 = __shfl(colv, j + 2);
    int v3 = __shfl(colv, j + 3);
    float f0 = __shfl(sv, j);
    float f1 = __shfl(sv, j + 1);
    float f2 = __shfl(sv, j + 2);
    float f3 = __shfl(sv, j + 3);
    if (f0 != 0.f) {
      unsigned int p = *(const unsigned int*)(hbf1 + (size_t)v0 * NH + lane * 2);
      ax += bf2f(p & 0xffff) * f0; ay += bf2f(p >> 16) * f0;
    }
    if (f1 != 0.f) {
      unsigned int p = *(const unsigned int*)(hbf1 + (size_t)v1 * NH + lane * 2);
      ax += bf2f(p & 0xffff) * f1; ay += bf2f(p >> 16) * f1;
    }
    if (f2 != 0.f) {
      unsigned int p = *(const unsigned int*)(hbf1 + (size_t)v2 * NH + lane * 2);
      ax += bf2f(p & 0xffff) * f2; ay += bf2f(p >> 16) * f2;
    }
    if (f3 != 0.f) {
      unsigned int p = *(const unsigned int*)(hbf1 + (size_t)v3 * NH + lane * 2);
      ax += bf2f(p & 0xffff) * f3; ay += bf2f(p >> 16) * f3;
    }
  }
  for (; j < m; ++j) {
    int v = __shfl(colv, j);
    float f = __shfl(sv, j);
    if (f != 0.f) {
      unsigned int p = *(const unsigned int*)(hbf1 + (size_t)v * NH + lane * 2);
      ax += bf2f(p & 0xffff) * f;
      ay += bf2f(p >> 16) * f;
    }
  }
  for (int jj = rs + 64; jj < re; ++jj) {      // deg>64 fallback (≈never)
    int v = col[jj];
    float f = s1m[v];
    if (f != 0.f) {
      unsigned int p = *(const unsigned int*)(hbf1 + (size_t)v * NH + lane * 2);
      ax += bf2f(p & 0xffff) * f;
      ay += bf2f(p >> 16) * f;
    }
  }
  unsigned int packed = ((unsigned int)f2bf(ay) << 16) | (unsigned int)f2bf(ax);
  *(unsigned int*)(agg2bf + (size_t)d * NH + lane * 2) = packed;
}

// ---------------------------------------------------------------------------
// conv2 GEMM via bf16 MFMA — barrier-free, LDS-free. r20: ONE row-group per
// wave, 1024 blocks (4 waves/SIMD vs r19's grid-limited 2) — occupancy over
// W-fragment reuse; per-row MFMA order unchanged (bitwise-identical output).
// A: agg2bf direct; root = hbf1*s1m (in-register). Output bf16, gated on
// s1m != 0. D layout: col=lane&15, row=(lane>>4)*4+reg (m89). XCD-swizzled.
// ---------------------------------------------------------------------------
__global__ __launch_bounds__(256) void k_gemm2(
    const unsigned short* __restrict__ agg2bf,
    const unsigned short* __restrict__ hbf1, const float* __restrict__ s1m,
    const unsigned short* __restrict__ Wfrag, const float* __restrict__ b2,
    const float* __restrict__ p2w, unsigned short* __restrict__ h2bf,
    float* __restrict__ s2) {
  int t = threadIdx.x;
  int bid = blockIdx.x;                 // 1024 blocks, 128 per XCD chunk
  int swz = (bid & 7) * 128 + (bid >> 3);
  int nb = swz * 64;
  int lane = t & 63, w = t >> 6;
  int row16 = lane & 15, kgrp = lane >> 4;
  int base = nb + 16 * w;               // wave owns rows base..base+15
  int r0 = base + row16;

  // ---- A fragments ----
  bf16x8 a0[8];
#pragma unroll
  for (int s = 0; s < 4; ++s) {
    int k = s * 32 + kgrp * 8;
    a0[s] = *(const bf16x8*)(agg2bf + (size_t)r0 * NH + k);
  }
  {
    float sc0 = s1m[r0];
    const unsigned short* S0 = hbf1 + (size_t)r0 * NH;
#pragma unroll
    for (int s = 0; s < 4; ++s) {
      int k = s * 32 + kgrp * 8;
      union { unsigned short us[8]; uint4 v; } i0;
      i0.v = *(const uint4*)(S0 + k);
      union { unsigned short us[8]; bf16x8 v; } p;
#pragma unroll
      for (int u = 0; u < 8; ++u) p.us[u] = f2bf(bf2f(i0.us[u]) * sc0);
      a0[4 + s] = p.v;
    }
  }

  // ---- MFMA: stream W fragments from L2 ----
  f32x4 acc0[8];
#pragma unroll
  for (int c = 0; c < 8; ++c) acc0[c] = (f32x4){0.f, 0.f, 0.f, 0.f};
  const bf16x8* WF = (const bf16x8*)Wfrag;
#pragma unroll
  for (int c = 0; c < 8; ++c) {
#pragma unroll
    for (int s = 0; s < 8; ++s) {
      bf16x8 wv = WF[(c * 8 + s) * 64 + lane];
      acc0[c] = __builtin_amdgcn_mfma_f32_16x16x32_bf16(a0[s], wv, acc0[c], 0, 0, 0);
    }
  }

  // ---- epilogue ----
  float bb[8], pw[8];
#pragma unroll
  for (int c = 0; c < 8; ++c) {
    bb[c] = b2[c * 16 + row16];
    pw[c] = p2w[c * 16 + row16];
  }
  float q2 = 0.f;
#pragma unroll
  for (int c = 0; c < 8; ++c) q2 += pw[c] * pw[c];
  q2 += __shfl_xor(q2, 1); q2 += __shfl_xor(q2, 2);
  q2 += __shfl_xor(q2, 4); q2 += __shfl_xor(q2, 8);
  float rnorm = rsqrtf(q2);

  int msr[4];
#pragma unroll
  for (int r = 0; r < 4; ++r) msr[r] = (s1m[base + kgrp * 4 + r] != 0.f);
  float pvp[4] = {0.f, 0.f, 0.f, 0.f};
#pragma unroll
  for (int c = 0; c < 8; ++c) {
#pragma unroll
    for (int r = 0; r < 4; ++r) {
      float u = fmaxf(acc0[c][r] + bb[c], 0.f);
      pvp[r] += u * pw[c];
      if (msr[r]) {                      // kept2 subset of kept1 -> safe skip
        int n = base + kgrp * 4 + r;
        h2bf[(size_t)n * NH + c * 16 + row16] = f2bf(u);
      }
    }
  }
#pragma unroll
  for (int r = 0; r < 4; ++r) {
    float pv = pvp[r];
    pv += __shfl_xor(pv, 1);
    pv += __shfl_xor(pv, 2);
    pv += __shfl_xor(pv, 4);
    pv += __shfl_xor(pv, 8);
    if (row16 == 0) {
      int n = base + kgrp * 4 + r;
      s2[n] = tanhf(pv * rnorm);
    }
  }
}

// ---------------------------------------------------------------------------
// readout2 partials — gates on s2m != 0 (no kept buffer anywhere)
// ---------------------------------------------------------------------------
__global__ __launch_bounds__(256) void k_readout2(
    const unsigned short* __restrict__ h, const float* __restrict__ s2m,
    float* __restrict__ psum, float* __restrict__ pmax) {
  int g = blockIdx.x >> 4, c = blockIdx.x & 15;
  int f = threadIdx.x & 127, half = threadIdx.x >> 7;
  int nbase = g * NPG + c * 64 + half;
  float sum = 0.f, mx = -1e30f;
  for (int i = 0; i < 64; i += 2) {
    int n = nbase + i;
    float sk = s2m[n];
    if (sk != 0.f) {
      float v = bf2f(h[(size_t)n * NH + f]) * sk;
      sum += v;
      mx = fmaxf(mx, v);
    }
  }
  int slot = blockIdx.x * 2 + half;
  psum[(size_t)slot * NH + f] = sum;
  pmax[(size_t)slot * NH + f] = mx;
}

// ---------------------------------------------------------------------------
// final combine (32 partial slots per graph per layer)
// ---------------------------------------------------------------------------
__global__ __launch_bounds__(256) void k_final(
    const float* __restrict__ psum1, const float* __restrict__ pmax1,
    const float* __restrict__ psum2, const float* __restrict__ pmax2,
    float* __restrict__ out) {
  int g = blockIdx.x, t = threadIdx.x;
  if (t < 128) {
    float a = 0.f, b = 0.f;
#pragma unroll
    for (int c = 0; c < 32; ++c) {
      a += psum1[(size_t)(g * 32 + c) * NH + t];
      b += psum2[(size_t)(g * 32 + c) * NH + t];
    }
    out[(size_t)g * 256 + t] = a / (float)KP1 + b / (float)KP2;
  } else {
    int f = t - 128;
    float a = -1e30f, b = -1e30f;
#pragma unroll
    for (int c = 0; c < 32; ++c) {
      a = fmaxf(a, pmax1[(size_t)(g * 32 + c) * NH + f]);
      b = fmaxf(b, pmax2[(size_t)(g * 32 + c) * NH + f]);
    }
    out[(size_t)g * 256 + t] = a + b;
  }
}

// ---------------------------------------------------------------------------
extern "C" void kernel_launch(void* const* d_in, const int* in_sizes, int n_in,
                              void* d_out, int out_size, void* d_ws, size_t ws_size,
                              hipStream_t stream) {
  const float* x     = (const float*)d_in[0];
  const int*   eidx  = (const int*)d_in[1];
  const int*   src   = eidx;
  const int*   dst   = eidx + EDGES;
  const float* W1rel = (const float*)d_in[3];
  const float* b1    = (const float*)d_in[4];
  const float* W1rt  = (const float*)d_in[5];
  const float* p1w   = (const float*)d_in[6];
  const float* W2rel = (const float*)d_in[7];
  const float* b2    = (const float*)d_in[8];
  const float* W2rt  = (const float*)d_in[9];
  const float* p2w   = (const float*)d_in[10];
  float* out = (float*)d_out;

  // workspace layout (floats)
  float* ws = (float*)d_ws;
  size_t off = 0;
  unsigned short* hbf1   = (unsigned short*)(ws + off); off += (size_t)NODES * NH / 2;
  unsigned short* h2bf   = (unsigned short*)(ws + off); off += (size_t)NODES * NH / 2;
  unsigned short* agg2bf = (unsigned short*)(ws + off); off += (size_t)NODES * NH / 2;
  float* agg1  = ws + off; off += (size_t)NODES * FIN;
  float* s1    = ws + off; off += NODES;
  float* s2    = ws + off; off += NODES;
  float* s1m   = ws + off; off += NODES;
  float* s2m   = ws + off; off += NODES;
  float* psum1 = ws + off; off += 2048 * NH;
  float* pmax1 = ws + off; off += 2048 * NH;
  float* psum2 = ws + off; off += 2048 * NH;
  float* pmax2 = ws + off; off += 2048 * NH;
  unsigned short* Wfrag = (unsigned short*)(ws + off); off += 16384; // 64 KB
  int*   rowptr  = (int*)(ws + off); off += NODES + 1;
  int*   col     = (int*)(ws + off); off += EDGES;

  // ---- CSR build + W fragment prep (one dispatch) ----
  k_csr<<<BATCH + 4, 1024, 0, stream>>>(src, dst, rowptr, col, W2rel, W2rt,
                                        Wfrag);

  // ---- layer 1 ----
  k_gather1<<<NODES / 16, 256, 0, stream>>>(x, rowptr, col, agg1);
  k_gemm1<<<NODES / 64, 256, 0, stream>>>(x, agg1, W1rel, b1, W1rt, p1w,
                                          hbf1, s1);
  k_topk<<<BATCH, 512, 0, stream>>>(s1, nullptr, s1m, KP1);

  // ---- merged: conv2 gather + layer-1 readout ----
  k_gather2ro<<<NG2BLK + 1024, 256, 0, stream>>>(hbf1, s1m, rowptr, col,
                                                 agg2bf, psum1, pmax1);

  // ---- layer 2 ----
  k_gemm2<<<NODES / 64, 256, 0, stream>>>(agg2bf, hbf1, s1m, Wfrag,
                                          b2, p2w, h2bf, s2);
  k_topk<<<BATCH, 512, 0, stream>>>(s2, s1m, s2m, KP2);
  k_readout2<<<1024, 256, 0, stream>>>(h2bf, s2m, psum2, pmax2);
  k_final<<<BATCH, 256, 0, stream>>>(psum1, pmax1, psum2, pmax2, out);
}

// Round 21
// 127.219 us; speedup vs baseline: 1.2691x; 1.1067x over previous
//
#include <hip/hip_runtime.h>
#include <hip/hip_bf16.h>
#include <cmath>

// Problem constants
#define BATCH   64
#define NPG     1024           // nodes per graph
#define NODES   65536          // BATCH*NPG
#define EDGES   524288
#define EPG     8192           // edges per graph (contiguous slice!)
#define FIN     14
#define NH      128
#define KP1     820
#define KP2     656
#define ASTR    15             // padded LDS stride for FIN tiles (2-way, free)
#define NG2BLK  16384          // gather2 blocks in merged dispatch

typedef __attribute__((ext_vector_type(8))) short bf16x8;
typedef __attribute__((ext_vector_type(4))) float f32x4;

static __device__ __forceinline__ unsigned short f2bf(float f) {
  __hip_bfloat16 h = __float2bfloat16(f);
  return *reinterpret_cast<unsigned short*>(&h);
}
static __device__ __forceinline__ float bf2f(unsigned int u16) {
  return __uint_as_float(u16 << 16);
}

// ---------------------------------------------------------------------------
// CSR build + Wfrag prep in ONE dispatch.
// Blocks 0..63: per-graph CSR; wave-level scan (__shfl_up, 5 barriers).
// Blocks 64..67: bf16 W2 fragment table.
// NOTE (r16 lesson): x stays f32 — bf16-izing conv1 inputs perturbs s1 and
// flips top-k boundary ranks (top-k is discontinuous in the score).
// ---------------------------------------------------------------------------
__global__ __launch_bounds__(1024) void k_csr(
    const int* __restrict__ src, const int* __restrict__ dst,
    int* __restrict__ rowptr, int* __restrict__ col,
    const float* __restrict__ W2rel, const float* __restrict__ W2rt,
    unsigned short* __restrict__ Wfrag) {
  int g = blockIdx.x, t = threadIdx.x;
  if (g >= BATCH) {                           // Wfrag builder blocks
    int id = (g - BATCH) * 1024 + t;          // 0..4095
    int lane = id & 63, sg = (id >> 6) & 7, c = id >> 9;
    const float* SW = (sg < 4) ? W2rel : W2rt;
    int o = c * 16 + (lane & 15);
    int k = (sg & 3) * 32 + (lane >> 4) * 8;
    float4 f0 = *(const float4*)(SW + (size_t)o * NH + k);
    float4 f1 = *(const float4*)(SW + (size_t)o * NH + k + 4);
    union { unsigned short us[8]; uint4 v; } p;
    p.us[0] = f2bf(f0.x); p.us[1] = f2bf(f0.y);
    p.us[2] = f2bf(f0.z); p.us[3] = f2bf(f0.w);
    p.us[4] = f2bf(f1.x); p.us[5] = f2bf(f1.y);
    p.us[6] = f2bf(f1.z); p.us[7] = f2bf(f1.w);
    *(uint4*)(Wfrag + (size_t)id * 8) = p.v;
    return;
  }
  __shared__ int cnt[NPG];
  __shared__ int wsum[16];
  int ebase = g * EPG;
  cnt[t] = 0;
  __syncthreads();
  int dl[8], sl[8];
#pragma unroll
  for (int i = 0; i < 8; ++i) {
    int e = ebase + t + i * 1024;
    dl[i] = dst[e] - g * NPG;
    sl[i] = src[e];
    atomicAdd(&cnt[dl[i]], 1);
  }
  __syncthreads();
  int v = cnt[t];
  int lane = t & 63, wid = t >> 6;
  int incl = v;                               // wave-level inclusive scan
#pragma unroll
  for (int d = 1; d < 64; d <<= 1) {
    int o = __shfl_up(incl, d);
    if (lane >= d) incl += o;
  }
  if (lane == 63) wsum[wid] = incl;
  __syncthreads();
  if (wid == 0) {
    int wv = (lane < 16) ? wsum[lane] : 0;
    int wi = wv;
#pragma unroll
    for (int d = 1; d < 16; d <<= 1) {
      int o = __shfl_up(wi, d);
      if (lane >= d) wi += o;
    }
    if (lane < 16) wsum[lane] = wi - wv;      // exclusive wave base
  }
  __syncthreads();
  int excl = incl - v + wsum[wid];
  rowptr[g * NPG + t] = ebase + excl;
  if (g == 0 && t == 0) rowptr[NODES] = EDGES;
  __syncthreads();
  cnt[t] = excl;                              // becomes local cursor
  __syncthreads();
#pragma unroll
  for (int i = 0; i < 8; ++i) {
    int pos = atomicAdd(&cnt[dl[i]], 1);
    col[ebase + pos] = sl[i];
  }
}

// ---------------------------------------------------------------------------
// conv1 aggregation via CSR gather over f32 x (score-path precision).
// Col indices preloaded per 16-lane group + shfl broadcast. XCD-swizzled.
// ---------------------------------------------------------------------------
__global__ __launch_bounds__(256) void k_gather1(
    const float* __restrict__ x, const int* __restrict__ rowptr,
    const int* __restrict__ col, float* __restrict__ agg1) {
  int bid = blockIdx.x;                       // 4096 blocks, 512 per XCD chunk
  int swz = (bid & 7) * 512 + (bid >> 3);
  int t = threadIdx.x;
  int gi = t >> 4;                            // node slot in block (0..15)
  int lane = t & 63;
  int sub = lane & 15;                        // position within 16-lane group
  int gb = lane & 48;                         // group base within wave
  int su = sub < FIN ? sub : FIN - 1;         // clamped feature index
  int n = swz * 16 + gi;
  int rs = rowptr[n], re = rowptr[n + 1];
  int deg = re - rs;
  int colv = (sub < deg) ? col[rs + sub] : 0;
  int m = deg < 16 ? deg : 16;
  float acc = 0.f;
  int nfull = m & ~3;
  int j = 0;
  for (; j < nfull; j += 4) {
    int v0 = __shfl(colv, gb + j);
    int v1 = __shfl(colv, gb + j + 1);
    int v2 = __shfl(colv, gb + j + 2);
    int v3 = __shfl(colv, gb + j + 3);
    float a0 = x[(size_t)v0 * FIN + su];
    float a1 = x[(size_t)v1 * FIN + su];
    float a2 = x[(size_t)v2 * FIN + su];
    float a3 = x[(size_t)v3 * FIN + su];
    acc += a0 + a1 + a2 + a3;
  }
  for (; j < m; ++j) {
    int v = __shfl(colv, gb + j);
    acc += x[(size_t)v * FIN + su];
  }
  for (int jj = rs + 16; jj < re; ++jj) {     // deg>16 fallback (~0.3%)
    int v = col[jj];
    acc += x[(size_t)v * FIN + su];
  }
  if (sub < FIN) agg1[(size_t)n * FIN + sub] = acc;
}

// ---------------------------------------------------------------------------
// conv1 GEMM + relu + fused pool1 score; OUTPUT IS BF16 (h only; s1 is f32).
// XCD-swizzled: hbf1 producer shares L2 slice with consumers. ASTR=15.
// ---------------------------------------------------------------------------
__global__ __launch_bounds__(256) void k_gemm1(
    const float* __restrict__ x, const float* __restrict__ agg1,
    const float* __restrict__ Wrel, const float* __restrict__ brel,
    const float* __restrict__ Wroot, const float* __restrict__ p1w,
    unsigned short* __restrict__ hbf1, float* __restrict__ s1) {
  __shared__ float As[64 * ASTR];
  __shared__ float Xs[64 * ASTR];
  __shared__ float Wl[2 * FIN][NH];
  int t = threadIdx.x;
  int bid = blockIdx.x;                       // 1024 blocks, 128 per XCD
  int swz = (bid & 7) * 128 + (bid >> 3);
  int nb = swz * 64;
  for (int i = t; i < 64 * FIN; i += 256) {
    int n = i / FIN, k = i - n * FIN;
    As[n * ASTR + k] = agg1[(size_t)nb * FIN + i];
    Xs[n * ASTR + k] = x[(size_t)nb * FIN + i];
  }
  for (int i = t; i < NH * FIN; i += 256) {
    int o = i / FIN, k = i - o * FIN;
    Wl[k][o]       = Wrel[i];
    Wl[k + FIN][o] = Wroot[i];
  }
  __syncthreads();
  int og = t & 15, ng = t >> 4, ra = ng * 4;
  float bb[8], pw[8];
#pragma unroll
  for (int j = 0; j < 4; ++j) {
    int c0 = og * 4 + j, c1 = 64 + og * 4 + j;
    bb[j] = brel[c0]; bb[j + 4] = brel[c1];
    pw[j] = p1w[c0];  pw[j + 4] = p1w[c1];
  }
  float q = 0.f;
#pragma unroll
  for (int j = 0; j < 8; ++j) q += pw[j] * pw[j];
  q += __shfl_xor(q, 1); q += __shfl_xor(q, 2);
  q += __shfl_xor(q, 4); q += __shfl_xor(q, 8);
  float rnorm = rsqrtf(q);

  float acc[4][8];
#pragma unroll
  for (int i = 0; i < 4; ++i)
#pragma unroll
    for (int j = 0; j < 8; ++j) acc[i][j] = bb[j];
#pragma unroll
  for (int k = 0; k < FIN; ++k) {
    float4 w0 = *(const float4*)&Wl[k][og * 4];
    float4 w1 = *(const float4*)&Wl[k][64 + og * 4];
#pragma unroll
    for (int i = 0; i < 4; ++i) {
      float a = As[(ra + i) * ASTR + k];
      acc[i][0] += a * w0.x; acc[i][1] += a * w0.y;
      acc[i][2] += a * w0.z; acc[i][3] += a * w0.w;
      acc[i][4] += a * w1.x; acc[i][5] += a * w1.y;
      acc[i][6] += a * w1.z; acc[i][7] += a * w1.w;
    }
  }
#pragma unroll
  for (int k = 0; k < FIN; ++k) {
    float4 w0 = *(const float4*)&Wl[FIN + k][og * 4];
    float4 w1 = *(const float4*)&Wl[FIN + k][64 + og * 4];
#pragma unroll
    for (int i = 0; i < 4; ++i) {
      float a = Xs[(ra + i) * ASTR + k];
      acc[i][0] += a * w0.x; acc[i][1] += a * w0.y;
      acc[i][2] += a * w0.z; acc[i][3] += a * w0.w;
      acc[i][4] += a * w1.x; acc[i][5] += a * w1.y;
      acc[i][6] += a * w1.z; acc[i][7] += a * w1.w;
    }
  }
#pragma unroll
  for (int i = 0; i < 4; ++i) {
    int n = nb + ra + i;
    float pv = 0.f;
    union { unsigned short us[4]; uint2 v; } o0, o1;
#pragma unroll
    for (int j = 0; j < 4; ++j) {
      float v0 = fmaxf(acc[i][j], 0.f);
      float v1 = fmaxf(acc[i][4 + j], 0.f);
      pv += v0 * pw[j] + v1 * pw[4 + j];
      o0.us[j] = f2bf(v0);
      o1.us[j] = f2bf(v1);
    }
    *(uint2*)(hbf1 + (size_t)n * NH + og * 4) = o0.v;
    *(uint2*)(hbf1 + (size_t)n * NH + 64 + og * 4) = o1.v;
    pv += __shfl_xor(pv, 1);
    pv += __shfl_xor(pv, 2);
    pv += __shfl_xor(pv, 4);
    pv += __shfl_xor(pv, 8);
    if (og == 0) s1[n] = tanhf(pv * rnorm);
  }
}

// ---------------------------------------------------------------------------
// exact per-graph top-K via 4-level RADIX SELECT: exact K-th largest ord in
// 4 histogram passes, coalesced sm_out writes.
// ---------------------------------------------------------------------------
__global__ __launch_bounds__(512) void k_topk(
    const float* __restrict__ score, const float* __restrict__ mask_sm,
    float* __restrict__ sm_out, int K) {
  __shared__ int hist[256];
  __shared__ int sh_bin, sh_base;
  int t = threadIdx.x, g = blockIdx.x;
  unsigned int ordv[2];
  float sval[2];
#pragma unroll
  for (int i = 0; i < 2; ++i) {
    int n = g * NPG + t + i * 512;
    float s = score[n];
    sval[i] = s;
    unsigned int u = __float_as_uint(s);
    unsigned int ord = (u & 0x80000000u) ? ~u : (u | 0x80000000u);
    if (mask_sm && mask_sm[n] == 0.f) ord = 0u;
    ordv[i] = ord;
  }
  unsigned int pref = 0u;
  int Krem = K;
  for (int lev = 3; lev >= 0; --lev) {
    int sh = lev * 8;
    unsigned int maskHigh = (lev == 3) ? 0u : (0xFFFFFFFFu << (sh + 8));
    if (t < 256) hist[t] = 0;
    __syncthreads();
#pragma unroll
    for (int i = 0; i < 2; ++i)
      if ((ordv[i] & maskHigh) == pref)
        atomicAdd(&hist[(ordv[i] >> sh) & 0xFF], 1);
    __syncthreads();
    if (t < 64) {                            // single-wave suffix scan
      int b3 = 255 - 4 * t;                  // lane owns bins b3..b3-3 (desc)
      int h0 = hist[b3], h1 = hist[b3 - 1];
      int h2 = hist[b3 - 2], h3 = hist[b3 - 3];
      int lsum = h0 + h1 + h2 + h3;
      int run = lsum;
#pragma unroll
      for (int d = 1; d < 64; d <<= 1) {
        int o = __shfl_up(run, d);
        if (t >= d) run += o;
      }
      int excl = run - lsum;                 // count in strictly-higher bins
      int c0 = excl + h0, c1 = c0 + h1, c2 = c1 + h2;
      if (excl < Krem && Krem <= c0)           { sh_bin = b3;     sh_base = excl; }
      else if (c0 < Krem && Krem <= c1)        { sh_bin = b3 - 1; sh_base = c0; }
      else if (c1 < Krem && Krem <= c2)        { sh_bin = b3 - 2; sh_base = c1; }
      else if (c2 < Krem && Krem <= c2 + h3)   { sh_bin = b3 - 3; sh_base = c2; }
    }
    __syncthreads();
    pref |= ((unsigned int)sh_bin) << sh;
    Krem -= sh_base;
    __syncthreads();
  }
#pragma unroll
  for (int i = 0; i < 2; ++i) {
    int n = g * NPG + t + i * 512;
    sm_out[n] = (ordv[i] >= pref) ? sval[i] : 0.f;
  }
}

// ---------------------------------------------------------------------------
// MERGED dispatch: gather2 (blocks 0..16383) + readout1 (blocks 16384..17407).
// gather2 r21: 2-edges-per-iteration split-wave (eh = lane>>5 picks the
// edge, fp = lane&31 picks 4 features via uint2 8B loads) — halves memory
// ops and shfls per edge; halves merged via shfl_xor(32). readout1 r21:
// uint 4B loads (2 features/thread, 4 row-groups, 4 slots/block).
// NO device-scope fences (r14 lesson).
// ---------------------------------------------------------------------------
__global__ __launch_bounds__(256) void k_gather2ro(
    const unsigned short* __restrict__ hbf1, const float* __restrict__ s1m,
    const int* __restrict__ rowptr, const int* __restrict__ col,
    unsigned short* __restrict__ agg2bf, float* __restrict__ psum,
    float* __restrict__ pmax) {
  int bid = blockIdx.x;
  if (bid >= NG2BLK) {                        // ---- readout1 path ----
    int rb = bid - NG2BLK;                    // 0..1023
    int g = rb >> 4, c = rb & 15;
    int t = threadIdx.x;
    int fp = t & 63, quad = t >> 6;           // fp: feature pair, quad: rows
    int nbase = g * NPG + c * 64 + quad;
    float sA = 0.f, sB = 0.f, mA = -1e30f, mB = -1e30f;
    for (int i = 0; i < 64; i += 4) {
      int n = nbase + i;
      float sk = s1m[n];
      if (sk != 0.f) {
        unsigned int p = *(const unsigned int*)(hbf1 + (size_t)n * NH + fp * 2);
        float a = bf2f(p & 0xffff) * sk;
        float b = bf2f(p >> 16) * sk;
        sA += a; sB += b;
        mA = fmaxf(mA, a); mB = fmaxf(mB, b);
      }
    }
    int slot = rb * 4 + quad;
    *(float2*)(psum + (size_t)slot * NH + fp * 2) = make_float2(sA, sB);
    *(float2*)(pmax + (size_t)slot * NH + fp * 2) = make_float2(mA, mB);
    return;
  }
  // ---- gather2 path ----
  int swz = (bid & 7) * 2048 + (bid >> 3);
  int wave = threadIdx.x >> 6, lane = threadIdx.x & 63;
  int d = swz * 4 + wave;
  if (s1m[d] == 0.f) return;                  // row never consumed downstream
  int rs = rowptr[d], re = rowptr[d + 1];
  int deg = re - rs;
  int colv = 0; float sv = 0.f;
  if (lane < deg) {
    colv = col[rs + lane];
    sv = s1m[colv];
  }
  int eh = lane >> 5;                          // edge half (0/1)
  int fp = lane & 31;                          // feature quad: fp*4..fp*4+3
  float a0 = 0.f, a1 = 0.f, a2 = 0.f, a3 = 0.f;
  int m = deg < 64 ? deg : 64;
#pragma unroll 4
  for (int j = 0; j < m; j += 2) {
    int idx = j + eh;                          // <= 63 (m even cap) or sv=0
    int v = __shfl(colv, idx);
    float f = __shfl(sv, idx);                 // 0 if idx >= deg
    if (f != 0.f) {
      uint2 p = *(const uint2*)(hbf1 + (size_t)v * NH + fp * 4);
      a0 += bf2f(p.x & 0xffff) * f; a1 += bf2f(p.x >> 16) * f;
      a2 += bf2f(p.y & 0xffff) * f; a3 += bf2f(p.y >> 16) * f;
    }
  }
  for (int jj = rs + 64 + eh; jj < re; jj += 2) {  // deg>64 fallback (≈never)
    int v = col[jj];
    float f = s1m[v];
    if (f != 0.f) {
      uint2 p = *(const uint2*)(hbf1 + (size_t)v * NH + fp * 4);
      a0 += bf2f(p.x & 0xffff) * f; a1 += bf2f(p.x >> 16) * f;
      a2 += bf2f(p.y & 0xffff) * f; a3 += bf2f(p.y >> 16) * f;
    }
  }
  a0 += __shfl_xor(a0, 32);
  a1 += __shfl_xor(a1, 32);
  a2 += __shfl_xor(a2, 32);
  a3 += __shfl_xor(a3, 32);
  if (eh == 0) {
    uint2 o;
    o.x = ((unsigned int)f2bf(a1) << 16) | (unsigned int)f2bf(a0);
    o.y = ((unsigned int)f2bf(a3) << 16) | (unsigned int)f2bf(a2);
    *(uint2*)(agg2bf + (size_t)d * NH + fp * 4) = o;
  }
}

// ---------------------------------------------------------------------------
// conv2 GEMM via bf16 MFMA — barrier-free, LDS-free, 1 row-group/wave,
// 1024 blocks (4 waves/SIMD). A: agg2bf direct; root = hbf1*s1m. Output
// bf16, gated on s1m != 0. D: col=lane&15, row=(lane>>4)*4+reg. XCD-swz.
// ---------------------------------------------------------------------------
__global__ __launch_bounds__(256) void k_gemm2(
    const unsigned short* __restrict__ agg2bf,
    const unsigned short* __restrict__ hbf1, const float* __restrict__ s1m,
    const unsigned short* __restrict__ Wfrag, const float* __restrict__ b2,
    const float* __restrict__ p2w, unsigned short* __restrict__ h2bf,
    float* __restrict__ s2) {
  int t = threadIdx.x;
  int bid = blockIdx.x;                 // 1024 blocks, 128 per XCD chunk
  int swz = (bid & 7) * 128 + (bid >> 3);
  int nb = swz * 64;
  int lane = t & 63, w = t >> 6;
  int row16 = lane & 15, kgrp = lane >> 4;
  int base = nb + 16 * w;               // wave owns rows base..base+15
  int r0 = base + row16;

  // ---- A fragments ----
  bf16x8 a0[8];
#pragma unroll
  for (int s = 0; s < 4; ++s) {
    int k = s * 32 + kgrp * 8;
    a0[s] = *(const bf16x8*)(agg2bf + (size_t)r0 * NH + k);
  }
  {
    float sc0 = s1m[r0];
    const unsigned short* S0 = hbf1 + (size_t)r0 * NH;
#pragma unroll
    for (int s = 0; s < 4; ++s) {
      int k = s * 32 + kgrp * 8;
      union { unsigned short us[8]; uint4 v; } i0;
      i0.v = *(const uint4*)(S0 + k);
      union { unsigned short us[8]; bf16x8 v; } p;
#pragma unroll
      for (int u = 0; u < 8; ++u) p.us[u] = f2bf(bf2f(i0.us[u]) * sc0);
      a0[4 + s] = p.v;
    }
  }

  // ---- MFMA: stream W fragments from L2 ----
  f32x4 acc0[8];
#pragma unroll
  for (int c = 0; c < 8; ++c) acc0[c] = (f32x4){0.f, 0.f, 0.f, 0.f};
  const bf16x8* WF = (const bf16x8*)Wfrag;
#pragma unroll
  for (int c = 0; c < 8; ++c) {
#pragma unroll
    for (int s = 0; s < 8; ++s) {
      bf16x8 wv = WF[(c * 8 + s) * 64 + lane];
      acc0[c] = __builtin_amdgcn_mfma_f32_16x16x32_bf16(a0[s], wv, acc0[c], 0, 0, 0);
    }
  }

  // ---- epilogue ----
  float bb[8], pw[8];
#pragma unroll
  for (int c = 0; c < 8; ++c) {
    bb[c] = b2[c * 16 + row16];
    pw[c] = p2w[c * 16 + row16];
  }
  float q2 = 0.f;
#pragma unroll
  for (int c = 0; c < 8; ++c) q2 += pw[c] * pw[c];
  q2 += __shfl_xor(q2, 1); q2 += __shfl_xor(q2, 2);
  q2 += __shfl_xor(q2, 4); q2 += __shfl_xor(q2, 8);
  float rnorm = rsqrtf(q2);

  int msr[4];
#pragma unroll
  for (int r = 0; r < 4; ++r) msr[r] = (s1m[base + kgrp * 4 + r] != 0.f);
  float pvp[4] = {0.f, 0.f, 0.f, 0.f};
#pragma unroll
  for (int c = 0; c < 8; ++c) {
#pragma unroll
    for (int r = 0; r < 4; ++r) {
      float u = fmaxf(acc0[c][r] + bb[c], 0.f);
      pvp[r] += u * pw[c];
      if (msr[r]) {                      // kept2 subset of kept1 -> safe skip
        int n = base + kgrp * 4 + r;
        h2bf[(size_t)n * NH + c * 16 + row16] = f2bf(u);
      }
    }
  }
#pragma unroll
  for (int r = 0; r < 4; ++r) {
    float pv = pvp[r];
    pv += __shfl_xor(pv, 1);
    pv += __shfl_xor(pv, 2);
    pv += __shfl_xor(pv, 4);
    pv += __shfl_xor(pv, 8);
    if (row16 == 0) {
      int n = base + kgrp * 4 + r;
      s2[n] = tanhf(pv * rnorm);
    }
  }
}

// ---------------------------------------------------------------------------
// readout2 partials — uint 4B loads, 4 row-groups, gates on s2m != 0
// ---------------------------------------------------------------------------
__global__ __launch_bounds__(256) void k_readout2(
    const unsigned short* __restrict__ h, const float* __restrict__ s2m,
    float* __restrict__ psum, float* __restrict__ pmax) {
  int g = blockIdx.x >> 4, c = blockIdx.x & 15;
  int t = threadIdx.x;
  int fp = t & 63, quad = t >> 6;
  int nbase = g * NPG + c * 64 + quad;
  float sA = 0.f, sB = 0.f, mA = -1e30f, mB = -1e30f;
  for (int i = 0; i < 64; i += 4) {
    int n = nbase + i;
    float sk = s2m[n];
    if (sk != 0.f) {
      unsigned int p = *(const unsigned int*)(h + (size_t)n * NH + fp * 2);
      float a = bf2f(p & 0xffff) * sk;
      float b = bf2f(p >> 16) * sk;
      sA += a; sB += b;
      mA = fmaxf(mA, a); mB = fmaxf(mB, b);
    }
  }
  int slot = blockIdx.x * 4 + quad;
  *(float2*)(psum + (size_t)slot * NH + fp * 2) = make_float2(sA, sB);
  *(float2*)(pmax + (size_t)slot * NH + fp * 2) = make_float2(mA, mB);
}

// ---------------------------------------------------------------------------
// final combine (64 partial slots per graph per layer)
// ---------------------------------------------------------------------------
__global__ __launch_bounds__(256) void k_final(
    const float* __restrict__ psum1, const float* __restrict__ pmax1,
    const float* __restrict__ psum2, const float* __restrict__ pmax2,
    float* __restrict__ out) {
  int g = blockIdx.x, t = threadIdx.x;
  if (t < 128) {
    float a = 0.f, b = 0.f;
#pragma unroll 8
    for (int c = 0; c < 64; ++c) {
      a += psum1[(size_t)(g * 64 + c) * NH + t];
      b += psum2[(size_t)(g * 64 + c) * NH + t];
    }
    out[(size_t)g * 256 + t] = a / (float)KP1 + b / (float)KP2;
  } else {
    int f = t - 128;
    float a = -1e30f, b = -1e30f;
#pragma unroll 8
    for (int c = 0; c < 64; ++c) {
      a = fmaxf(a, pmax1[(size_t)(g * 64 + c) * NH + f]);
      b = fmaxf(b, pmax2[(size_t)(g * 64 + c) * NH + f]);
    }
    out[(size_t)g * 256 + t] = a + b;
  }
}

// ---------------------------------------------------------------------------
extern "C" void kernel_launch(void* const* d_in, const int* in_sizes, int n_in,
                              void* d_out, int out_size, void* d_ws, size_t ws_size,
                              hipStream_t stream) {
  const float* x     = (const float*)d_in[0];
  const int*   eidx  = (const int*)d_in[1];
  const int*   src   = eidx;
  const int*   dst   = eidx + EDGES;
  const float* W1rel = (const float*)d_in[3];
  const float* b1    = (const float*)d_in[4];
  const float* W1rt  = (const float*)d_in[5];
  const float* p1w   = (const float*)d_in[6];
  const float* W2rel = (const float*)d_in[7];
  const float* b2    = (const float*)d_in[8];
  const float* W2rt  = (const float*)d_in[9];
  const float* p2w   = (const float*)d_in[10];
  float* out = (float*)d_out;

  // workspace layout (floats)
  float* ws = (float*)d_ws;
  size_t off = 0;
  unsigned short* hbf1   = (unsigned short*)(ws + off); off += (size_t)NODES * NH / 2;
  unsigned short* h2bf   = (unsigned short*)(ws + off); off += (size_t)NODES * NH / 2;
  unsigned short* agg2bf = (unsigned short*)(ws + off); off += (size_t)NODES * NH / 2;
  float* agg1  = ws + off; off += (size_t)NODES * FIN;
  float* s1    = ws + off; off += NODES;
  float* s2    = ws + off; off += NODES;
  float* s1m   = ws + off; off += NODES;
  float* s2m   = ws + off; off += NODES;
  float* psum1 = ws + off; off += 4096 * NH;
  float* pmax1 = ws + off; off += 4096 * NH;
  float* psum2 = ws + off; off += 4096 * NH;
  float* pmax2 = ws + off; off += 4096 * NH;
  unsigned short* Wfrag = (unsigned short*)(ws + off); off += 16384; // 64 KB
  int*   rowptr  = (int*)(ws + off); off += NODES + 1;
  int*   col     = (int*)(ws + off); off += EDGES;

  // ---- CSR build + W fragment prep (one dispatch) ----
  k_csr<<<BATCH + 4, 1024, 0, stream>>>(src, dst, rowptr, col, W2rel, W2rt,
                                        Wfrag);

  // ---- layer 1 ----
  k_gather1<<<NODES / 16, 256, 0, stream>>>(x, rowptr, col, agg1);
  k_gemm1<<<NODES / 64, 256, 0, stream>>>(x, agg1, W1rel, b1, W1rt, p1w,
                                          hbf1, s1);
  k_topk<<<BATCH, 512, 0, stream>>>(s1, nullptr, s1m, KP1);

  // ---- merged: conv2 gather + layer-1 readout ----
  k_gather2ro<<<NG2BLK + 1024, 256, 0, stream>>>(hbf1, s1m, rowptr, col,
                                                 agg2bf, psum1, pmax1);

  // ---- layer 2 ----
  k_gemm2<<<NODES / 64, 256, 0, stream>>>(agg2bf, hbf1, s1m, Wfrag,
                                          b2, p2w, h2bf, s2);
  k_topk<<<BATCH, 512, 0, stream>>>(s2, s1m, s2m, KP2);
  k_readout2<<<1024, 256, 0, stream>>>(h2bf, s2m, psum2, pmax2);
  k_final<<<BATCH, 256, 0, stream>>>(psum1, pmax1, psum2, pmax2, out);
}